// Round 1
// baseline (241.539 us; speedup 1.0000x reference)
//
#include <hip/hip_runtime.h>
#include <hip/hip_bf16.h>

#define NH  12
#define HD  64
#define DIM 768
#define SEQ 2048
#define NB  4
#define MM  (NB*SEQ)   // 8192 rows
#define NKB (SEQ/64)   // 32 key-blocks per head

typedef short    v8s  __attribute__((ext_vector_type(8)));   // 8 x bf16 (4 VGPRs)
typedef float    v4f  __attribute__((ext_vector_type(4)));
typedef float    v16f __attribute__((ext_vector_type(16)));
typedef unsigned v4u  __attribute__((ext_vector_type(4)));

#if __has_builtin(__builtin_amdgcn_exp2f)
#define EXP2(x) __builtin_amdgcn_exp2f(x)
#else
#define EXP2(x) __builtin_exp2f(x)
#endif

// round-to-nearest-even f32 -> bf16
static __device__ __forceinline__ unsigned short f2b(float f) {
    unsigned int u = __float_as_uint(f);
    return (unsigned short)((u + 0x7FFFu + ((u >> 16) & 1u)) >> 16);
}
// single-instruction pack: dst = bf16(lo) | bf16(hi)<<16 (RNE)
static __device__ __forceinline__ unsigned cvtpk(float lo, float hi) {
    unsigned r;
    asm("v_cvt_pk_bf16_f32 %0, %1, %2" : "=v"(r) : "v"(lo), "v"(hi));
    return r;
}
// async global->LDS DMA, 16B/lane; LDS base wave-uniform, writes base+lane*16
static __device__ __forceinline__ void g2l16(const unsigned short* g, unsigned short* l) {
    __builtin_amdgcn_global_load_lds(
        (const __attribute__((address_space(1))) void*)g,
        (__attribute__((address_space(3))) void*)l, 16, 0, 0);
}

__global__ void cast_f32_bf16(const float* __restrict__ in,
                              unsigned short* __restrict__ out, int n4) {
    int i = blockIdx.x * blockDim.x + threadIdx.x;
    if (i < n4) {
        float4 v = reinterpret_cast<const float4*>(in)[i];
        ushort4 o;
        o.x = f2b(v.x); o.y = f2b(v.y); o.z = f2b(v.z); o.w = f2b(v.w);
        reinterpret_cast<ushort4*>(out)[i] = o;
    }
}

__global__ void cast4_f32_bf16(const float* __restrict__ i0, const float* __restrict__ i1,
                               const float* __restrict__ i2, const float* __restrict__ i3,
                               unsigned short* __restrict__ o0, unsigned short* __restrict__ o1,
                               unsigned short* __restrict__ o2, unsigned short* __restrict__ o3,
                               int n4) {
    int i = blockIdx.x * blockDim.x + threadIdx.x;
    if (i >= n4) return;
    const float* in; unsigned short* out;
    switch (blockIdx.y) {
        case 0: in = i0; out = o0; break;
        case 1: in = i1; out = o1; break;
        case 2: in = i2; out = o2; break;
        default: in = i3; out = o3; break;
    }
    float4 v = reinterpret_cast<const float4*>(in)[i];
    ushort4 o;
    o.x = f2b(v.x); o.y = f2b(v.y); o.z = f2b(v.z); o.w = f2b(v.w);
    reinterpret_cast<ushort4*>(out)[i] = o;
}

// Merged QKV: grid (MM/128, NH). One block computes Q,K,V for 128 rows x one
// head (64 features). A staged once per kb; 3 weight tiles; 48 MFMA/phase/wave.
// K and V are both written FRAGMENT-NATIVE (MFMA A-frag layout) so attn reads
// them as coalesced global loads with no LDS staging.
__global__ __launch_bounds__(256, 3) void gemm_qkv(
    const unsigned short* __restrict__ A,
    const unsigned short* __restrict__ Wq,
    const unsigned short* __restrict__ Wk,
    const unsigned short* __restrict__ Wv,
    const float* __restrict__ bq,
    const float* __restrict__ bk,
    const float* __restrict__ bvp,
    unsigned short* __restrict__ Qb,
    unsigned short* __restrict__ Kfo,
    unsigned short* __restrict__ Vf)
{
    __shared__ __align__(16) unsigned short As[128 * 64];      // 16 KB
    __shared__ __align__(16) unsigned short Bs[3][64 * 64];    // 24 KB

    const int tid  = threadIdx.x;
    const int w    = tid >> 6, lane = tid & 63;
    const int quad = lane >> 4, l16 = lane & 15;
    const int wm   = w & 1,  wn = w >> 1;
    const int lane8 = lane >> 3, sc = lane & 7;
    const int m0   = blockIdx.x * 128;
    const int h    = blockIdx.y;
    const int n0   = h * 64;

    v4f acc[3][4][2];
    #pragma unroll
    for (int s = 0; s < 3; ++s)
        #pragma unroll
        for (int i = 0; i < 4; ++i)
            #pragma unroll
            for (int j = 0; j < 2; ++j)
                acc[s][i][j] = v4f{0.f, 0.f, 0.f, 0.f};

    for (int kb = 0; kb < DIM; kb += 64) {
        __syncthreads();
        #pragma unroll
        for (int t = 0; t < 4; ++t) {
            int r8 = w * 32 + t * 8;
            int r  = r8 + lane8;
            int gch = sc ^ (r & 7);
            g2l16(&A[(size_t)(m0 + r) * DIM + kb + gch * 8], &As[r8 * 64]);
        }
        #pragma unroll
        for (int u = 0; u < 6; ++u) {
            int G = w * 6 + u;               // 0..23: set = G>>3, rowgrp = G&7
            int set = G >> 3, rg = G & 7;
            int row = rg * 8 + lane8;
            int gch = sc ^ (row & 7);
            const unsigned short* Wp = (set == 0) ? Wq : (set == 1) ? Wk : Wv;
            g2l16(&Wp[(size_t)(n0 + row) * DIM + kb + gch * 8], &Bs[set][rg * 8 * 64]);
        }
        __syncthreads();
        #pragma unroll
        for (int kk = 0; kk < 64; kk += 32) {
            int chb = kk >> 3;
            v8s a[4];
            #pragma unroll
            for (int i = 0; i < 4; ++i) {
                int m = wm * 64 + i * 16 + l16;
                a[i] = *reinterpret_cast<const v8s*>(
                    &As[m * 64 + (((chb + quad) ^ (m & 7)) << 3)]);
            }
            #pragma unroll
            for (int s = 0; s < 3; ++s) {
                v8s b[2];
                #pragma unroll
                for (int j = 0; j < 2; ++j) {
                    int n = wn * 32 + j * 16 + l16;
                    b[j] = *reinterpret_cast<const v8s*>(
                        &Bs[s][n * 64 + (((chb + quad) ^ (n & 7)) << 3)]);
                }
                #pragma unroll
                for (int i = 0; i < 4; ++i)
                    #pragma unroll
                    for (int j = 0; j < 2; ++j)
                        acc[s][i][j] = __builtin_amdgcn_mfma_f32_16x16x32_bf16(
                            a[i], b[j], acc[s][i][j], 0, 0, 0);
            }
        }
    }

    // ---- epilogues ----
    // Q: [bh][seq][hd], pre-scaled by 1/8 * log2(e)
    #pragma unroll
    for (int i = 0; i < 4; ++i) {
        #pragma unroll
        for (int j = 0; j < 2; ++j) {
            int hd = wn * 32 + j * 16 + l16;
            float bias_v = bq[n0 + hd];
            #pragma unroll
            for (int r = 0; r < 4; ++r) {
                int gm = m0 + wm * 64 + i * 16 + quad * 4 + r;
                int bb = gm >> 11, sq = gm & (SEQ - 1);
                Qb[((size_t)(bb * NH + h) * SEQ + sq) * HD + hd] =
                    f2b((acc[0][i][j][r] + bias_v) * 0.1803368801f);
            }
        }
    }
    // K: fragment-native Kf[bh][t][kh*4+c][lane(=hdbit3*32 + key&31)][8]
    // attn reads: lane (half,l31) gets K[key = t*64 + kh*32 + l31][c*16 + half*8 + j]
    #pragma unroll
    for (int i = 0; i < 4; ++i) {
        int kh = i >> 1;
        #pragma unroll
        for (int j = 0; j < 2; ++j) {
            int hd = wn * 32 + j * 16 + l16;
            int c  = hd >> 4;              // = wn*2 + j
            int half_a = (l16 >> 3) & 1;   // hd bit 3
            int jj = l16 & 7;              // hd low 3 bits
            float bias_v = bk[n0 + hd];
            int gm0 = m0 + wm * 64 + i * 16 + quad * 4;
            int bb = gm0 >> 11, sk = gm0 & (SEQ - 1);
            int t = sk >> 6;
            int l31k = (i & 1) * 16 + quad * 4;          // + r below
            size_t frag = ((size_t)(bb * NH + h) * NKB + t) * 8 + kh * 4 + c;
            unsigned short* dst = &Kfo[frag * 512 + (half_a * 32 + l31k) * 8 + jj];
            #pragma unroll
            for (int r = 0; r < 4; ++r)
                dst[r * 8] = f2b(acc[1][i][j][r] + bias_v);
        }
    }
    // V: fragment-native Vf[bh][kbi][hb*4+c][lane][8]
    #pragma unroll
    for (int i = 0; i < 4; ++i) {
        #pragma unroll
        for (int j = 0; j < 2; ++j) {
            int hd = wn * 32 + j * 16 + l16;
            int hb = hd >> 5, l31v = hd & 31;
            float bias_v = bvp[n0 + hd];
            int gm0 = m0 + wm * 64 + i * 16 + quad * 4;
            int bb = gm0 >> 11, sk = gm0 & (SEQ - 1);
            int kbi = sk >> 6;
            int halfv = quad >> 1, j0 = (quad & 1) * 4;
            ushort4 pkv;
            pkv.x = f2b(acc[2][i][j][0] + bias_v);
            pkv.y = f2b(acc[2][i][j][1] + bias_v);
            pkv.z = f2b(acc[2][i][j][2] + bias_v);
            pkv.w = f2b(acc[2][i][j][3] + bias_v);
            size_t frag = ((size_t)(bb * NH + h) * NKB + kbi) * 8 + hb * 4 + i;
            *reinterpret_cast<ushort4*>(
                &Vf[frag * 512 + (halfv * 32 + l31v) * 8 + j0]) = pkv;
        }
    }
}

// Output projection: 128x64 tiles, grid (64, 12) = 768 blocks = 3 WG/CU even.
__global__ __launch_bounds__(256, 3) void gemm_o(
    const unsigned short* __restrict__ A,
    const unsigned short* __restrict__ W,
    const float* __restrict__ bias,
    float* __restrict__ out)
{
    __shared__ __align__(16) unsigned short As[128 * 64];   // 16 KB
    __shared__ __align__(16) unsigned short Bs[64 * 64];    // 8 KB

    const int tid  = threadIdx.x;
    const int w    = tid >> 6, lane = tid & 63;
    const int quad = lane >> 4, l16 = lane & 15;
    const int wm   = w & 1,  wn = w >> 1;
    const int lane8 = lane >> 3, sc = lane & 7;
    const int m0  = blockIdx.x * 128;
    const int n0l = blockIdx.y * 64;

    v4f acc[4][2];
    #pragma unroll
    for (int i = 0; i < 4; ++i)
        #pragma unroll
        for (int j = 0; j < 2; ++j)
            acc[i][j] = v4f{0.f, 0.f, 0.f, 0.f};

    for (int kb = 0; kb < DIM; kb += 64) {
        __syncthreads();
        #pragma unroll
        for (int t = 0; t < 4; ++t) {
            int r8 = w * 32 + t * 8;
            int r  = r8 + lane8;
            int gch = sc ^ (r & 7);
            g2l16(&A[(size_t)(m0 + r) * DIM + kb + gch * 8], &As[r8 * 64]);
        }
        #pragma unroll
        for (int t = 0; t < 2; ++t) {
            int r8 = (w * 2 + t) * 8;
            int r  = r8 + lane8;
            int gch = sc ^ (r & 7);
            g2l16(&W[(size_t)(n0l + r) * DIM + kb + gch * 8], &Bs[r8 * 64]);
        }
        __syncthreads();
        #pragma unroll
        for (int kk = 0; kk < 64; kk += 32) {
            v8s a[4], b[2];
            int chb = kk >> 3;
            #pragma unroll
            for (int i = 0; i < 4; ++i) {
                int m = wm * 64 + i * 16 + l16;
                a[i] = *reinterpret_cast<const v8s*>(
                    &As[m * 64 + (((chb + quad) ^ (m & 7)) << 3)]);
            }
            #pragma unroll
            for (int j = 0; j < 2; ++j) {
                int n = wn * 32 + j * 16 + l16;
                b[j] = *reinterpret_cast<const v8s*>(
                    &Bs[n * 64 + (((chb + quad) ^ (n & 7)) << 3)]);
            }
            #pragma unroll
            for (int i = 0; i < 4; ++i)
                #pragma unroll
                for (int j = 0; j < 2; ++j)
                    acc[i][j] = __builtin_amdgcn_mfma_f32_16x16x32_bf16(a[i], b[j], acc[i][j], 0, 0, 0);
        }
    }

    #pragma unroll
    for (int i = 0; i < 4; ++i) {
        #pragma unroll
        for (int j = 0; j < 2; ++j) {
            int gn = n0l + wn * 32 + j * 16 + l16;
            float bias_v = bias[gn];
            #pragma unroll
            for (int r = 0; r < 4; ++r) {
                int gm = m0 + wm * 64 + i * 16 + quad * 4 + r;
                out[(size_t)gm * DIM + gn] = acc[i][j][r] + bias_v;
            }
        }
    }
}

// Transposed flash attention — ZERO LDS / ZERO BARRIERS.
// Both K and V are fragment-native in global memory (written by gemm_qkv),
// read as coalesced 16B/lane loads, single-buffer register prefetch one tile
// ahead (K prefetched right after QK^T consumes it; V right after PV).
// Each of the 4 waves per block free-runs; no inter-wave coupling at all.
__global__ __launch_bounds__(256, 3) void attn(
    const unsigned short* __restrict__ Q,
    const unsigned short* __restrict__ Kf,
    const unsigned short* __restrict__ Vf,
    unsigned short* __restrict__ ctx)
{
    const int tid  = threadIdx.x;
    const int w    = tid >> 6, lane = tid & 63;
    const int l31  = lane & 31, half = lane >> 5;
    const int bh   = blockIdx.y;
    const int b    = bh / NH, h = bh % NH;
    const int q0   = blockIdx.x * 128 + w * 32;

    const unsigned short* Qp = Q  + ((size_t)bh * SEQ + q0) * HD;
    const unsigned short* Vh = Vf + (size_t)bh * (NKB * 8 * 512) + lane * 8;
    const unsigned short* Kh = Kf + (size_t)bh * (NKB * 8 * 512) + lane * 8;

    // Q B-frag: B[n=q=l31][k = c*16 + half*8 + j] (pre-scaled by 0.125*log2e)
    v8s bq[4];
    #pragma unroll
    for (int c = 0; c < 4; ++c)
        bq[c] = *reinterpret_cast<const v8s*>(&Qp[l31 * HD + c * 16 + half * 8]);

    // K/V A-frags for tile 0 (coalesced: consecutive lanes -> consecutive 16B)
    v8s ka[2][4], va[2][4];
    #pragma unroll
    for (int g = 0; g < 8; ++g)
        reinterpret_cast<v8s*>(ka)[g] = *reinterpret_cast<const v8s*>(&Kh[g * 512]);
    #pragma unroll
    for (int g = 0; g < 8; ++g)
        reinterpret_cast<v8s*>(va)[g] = *reinterpret_cast<const v8s*>(&Vh[g * 512]);

    v16f o0, o1, Z;
    #pragma unroll
    for (int i = 0; i < 16; ++i) { o0[i] = 0.f; o1[i] = 0.f; Z[i] = 0.f; }
    float li = 0.f;

    for (int it = 0; it < NKB; ++it) {
        // S^T[key][q]: two independent 4-deep MFMA chains (keys 0..31 / 32..63)
        v16f s0 = __builtin_amdgcn_mfma_f32_32x32x16_bf16(ka[0][0], bq[0], Z, 0, 0, 0);
        v16f s1 = __builtin_amdgcn_mfma_f32_32x32x16_bf16(ka[1][0], bq[0], Z, 0, 0, 0);
        #pragma unroll
        for (int c = 1; c < 4; ++c) {
            s0 = __builtin_amdgcn_mfma_f32_32x32x16_bf16(ka[0][c], bq[c], s0, 0, 0, 0);
            s1 = __builtin_amdgcn_mfma_f32_32x32x16_bf16(ka[1][c], bq[c], s1, 0, 0, 0);
        }

        // prefetch next K tile; lands during softmax+PV below (vmcnt counted
        // wait is inserted by the compiler before next iteration's first MFMA)
        {
            const unsigned short* Kn = Kh + (size_t)(it + 1 < NKB ? it + 1 : it) * (8 * 512);
            #pragma unroll
            for (int g = 0; g < 8; ++g)
                reinterpret_cast<v8s*>(ka)[g] = *reinterpret_cast<const v8s*>(&Kn[g * 512]);
        }

        // exp2 + lane-local li + pack key-pairs (1 instr per pair via cvt_pk)
        unsigned pk[8][2];
        #pragma unroll
        for (int g = 0; g < 4; ++g) {
            float e0 = EXP2(s0[4*g+0]), e1 = EXP2(s0[4*g+1]);
            float e2 = EXP2(s0[4*g+2]), e3 = EXP2(s0[4*g+3]);
            li += (e0 + e1) + (e2 + e3);
            pk[g][0] = cvtpk(e0, e1);
            pk[g][1] = cvtpk(e2, e3);
            float f0 = EXP2(s1[4*g+0]), f1 = EXP2(s1[4*g+1]);
            float f2 = EXP2(s1[4*g+2]), f3 = EXP2(s1[4*g+3]);
            li += (f0 + f1) + (f2 + f3);
            pk[4+g][0] = cvtpk(f0, f1);
            pk[4+g][1] = cvtpk(f2, f3);
        }

        // P^T B-frags: partner (lane^32) holds the complementary 4-key blocks.
        #pragma unroll
        for (int cp = 0; cp < 4; ++cp) {
            unsigned a0 = pk[2*cp][0],   a1 = pk[2*cp][1];
            unsigned b0 = pk[2*cp+1][0], b1 = pk[2*cp+1][1];
            unsigned u0 = half ? a0 : b0;      // what my partner needs from me
            unsigned u1 = half ? a1 : b1;
            unsigned x0 = __shfl_xor(u0, 32);
            unsigned x1 = __shfl_xor(u1, 32);
            v4u fw;
            fw.x = half ? x0 : a0;
            fw.y = half ? x1 : a1;
            fw.z = half ? b0 : x0;
            fw.w = half ? b1 : x1;
            v8s pf = __builtin_bit_cast(v8s, fw);
            o0 = __builtin_amdgcn_mfma_f32_32x32x16_bf16(va[0][cp], pf, o0, 0, 0, 0);
            o1 = __builtin_amdgcn_mfma_f32_32x32x16_bf16(va[1][cp], pf, o1, 0, 0, 0);
        }

        // prefetch next V tile (lands during next QK^T + softmax)
        {
            const unsigned short* Vn = Vh + (size_t)(it + 1 < NKB ? it + 1 : it) * (8 * 512);
            #pragma unroll
            for (int g = 0; g < 8; ++g)
                reinterpret_cast<v8s*>(va)[g] = *reinterpret_cast<const v8s*>(&Vn[g * 512]);
        }
    }

    // li total = own 32 keys + partner's 32 keys (same q)
    float inv = 1.0f / (li + __shfl_xor(li, 32));

    // O^T: lane holds q = q0+l31; rows hd = (reg&3)+8*(reg>>2)+4*half (+32 for o1)
    const int q = q0 + l31;
    size_t base = ((size_t)(b * SEQ + q)) * DIM + h * HD;
    #pragma unroll
    for (int g = 0; g < 4; ++g) {
        int hd0 = 8 * g + 4 * half;
        uint2 u0, u1;
        u0.x = cvtpk(o0[4*g+0] * inv, o0[4*g+1] * inv);
        u0.y = cvtpk(o0[4*g+2] * inv, o0[4*g+3] * inv);
        u1.x = cvtpk(o1[4*g+0] * inv, o1[4*g+1] * inv);
        u1.y = cvtpk(o1[4*g+2] * inv, o1[4*g+3] * inv);
        *reinterpret_cast<uint2*>(&ctx[base + hd0])      = u0;
        *reinterpret_cast<uint2*>(&ctx[base + 32 + hd0]) = u1;
    }
}

extern "C" void kernel_launch(void* const* d_in, const int* in_sizes, int n_in,
                              void* d_out, int out_size, void* d_ws, size_t ws_size,
                              hipStream_t stream) {
    const float* x  = (const float*)d_in[0];
    const float* qw = (const float*)d_in[1]; const float* qb = (const float*)d_in[2];
    const float* kw = (const float*)d_in[3]; const float* kb = (const float*)d_in[4];
    const float* vw = (const float*)d_in[5]; const float* vb = (const float*)d_in[6];
    const float* ow = (const float*)d_in[7]; const float* ob = (const float*)d_in[8];
    float* out = (float*)d_out;

    char* ws = (char*)d_ws;
    size_t off = 0;
    auto alloc = [&](size_t bytes) -> unsigned short* {
        unsigned short* p = (unsigned short*)(ws + off);
        off += (bytes + 255) & ~(size_t)255;
        return p;
    };
    const size_t XB = (size_t)MM * DIM * 2;
    const size_t WB = (size_t)DIM * DIM * 2;
    const size_t QB = (size_t)NB * NH * SEQ * HD * 2;

    unsigned short* xb  = alloc(XB);
    unsigned short* wqb = alloc(WB);
    unsigned short* wkb = alloc(WB);
    unsigned short* wvb = alloc(WB);
    unsigned short* wob = alloc(WB);
    unsigned short* Qb  = alloc(QB);
    unsigned short* Kfb = alloc(QB);   // fragment-native K
    unsigned short* Vfb = alloc(QB);   // fragment-native V
    unsigned short* ctx = alloc(XB);

    const int n4x = MM * DIM / 4;
    const int n4w = DIM * DIM / 4;
    cast_f32_bf16<<<(n4x + 255) / 256, 256, 0, stream>>>(x, xb, n4x);
    cast4_f32_bf16<<<dim3((n4w + 255) / 256, 4), 256, 0, stream>>>(
        qw, kw, vw, ow, wqb, wkb, wvb, wob, n4w);

    gemm_qkv<<<dim3(MM / 128, NH), 256, 0, stream>>>(
        xb, wqb, wkb, wvb, qb, kb, vb, Qb, Kfb, Vfb);

    attn<<<dim3(SEQ / 128, NB * NH), 256, 0, stream>>>(Qb, Kfb, Vfb, ctx);

    gemm_o<<<dim3(MM / 128, DIM / 64), 256, 0, stream>>>(ctx, wob, ob, out);
}

// Round 2
// 211.146 us; speedup vs baseline: 1.1439x; 1.1439x over previous
//
#include <hip/hip_runtime.h>
#include <hip/hip_bf16.h>

#define NH  12
#define HD  64
#define DIM 768
#define SEQ 2048
#define NB  4
#define MM  (NB*SEQ)   // 8192 rows
#define NKB (SEQ/64)   // 32 key-blocks per head

typedef short    v8s  __attribute__((ext_vector_type(8)));   // 8 x bf16 (4 VGPRs)
typedef float    v4f  __attribute__((ext_vector_type(4)));
typedef float    v16f __attribute__((ext_vector_type(16)));
typedef unsigned v4u  __attribute__((ext_vector_type(4)));

#if __has_builtin(__builtin_amdgcn_exp2f)
#define EXP2(x) __builtin_amdgcn_exp2f(x)
#else
#define EXP2(x) __builtin_exp2f(x)
#endif

// round-to-nearest-even f32 -> bf16
static __device__ __forceinline__ unsigned short f2b(float f) {
    unsigned int u = __float_as_uint(f);
    return (unsigned short)((u + 0x7FFFu + ((u >> 16) & 1u)) >> 16);
}
// single-instruction pack: dst = bf16(lo) | bf16(hi)<<16 (RNE)
static __device__ __forceinline__ unsigned cvtpk(float lo, float hi) {
    unsigned r;
    asm("v_cvt_pk_bf16_f32 %0, %1, %2" : "=v"(r) : "v"(lo), "v"(hi));
    return r;
}
// async global->LDS DMA, 16B/lane; LDS base wave-uniform, writes base+lane*16
static __device__ __forceinline__ void g2l16(const unsigned short* g, unsigned short* l) {
    __builtin_amdgcn_global_load_lds(
        (const __attribute__((address_space(1))) void*)g,
        (__attribute__((address_space(3))) void*)l, 16, 0, 0);
}

__global__ void cast_f32_bf16(const float* __restrict__ in,
                              unsigned short* __restrict__ out, int n4) {
    int i = blockIdx.x * blockDim.x + threadIdx.x;
    if (i < n4) {
        float4 v = reinterpret_cast<const float4*>(in)[i];
        ushort4 o;
        o.x = f2b(v.x); o.y = f2b(v.y); o.z = f2b(v.z); o.w = f2b(v.w);
        reinterpret_cast<ushort4*>(out)[i] = o;
    }
}

__global__ void cast4_f32_bf16(const float* __restrict__ i0, const float* __restrict__ i1,
                               const float* __restrict__ i2, const float* __restrict__ i3,
                               unsigned short* __restrict__ o0, unsigned short* __restrict__ o1,
                               unsigned short* __restrict__ o2, unsigned short* __restrict__ o3,
                               int n4) {
    int i = blockIdx.x * blockDim.x + threadIdx.x;
    if (i >= n4) return;
    const float* in; unsigned short* out;
    switch (blockIdx.y) {
        case 0: in = i0; out = o0; break;
        case 1: in = i1; out = o1; break;
        case 2: in = i2; out = o2; break;
        default: in = i3; out = o3; break;
    }
    float4 v = reinterpret_cast<const float4*>(in)[i];
    ushort4 o;
    o.x = f2b(v.x); o.y = f2b(v.y); o.z = f2b(v.z); o.w = f2b(v.w);
    reinterpret_cast<ushort4*>(out)[i] = o;
}

// Merged QKV: grid (MM/128, NH). One block computes Q,K,V for 128 rows x one
// head (64 features). K and V written FRAGMENT-NATIVE (MFMA A-frag layout):
// attn DMA-stages K tiles linearly into LDS and streams V as register frags.
__global__ __launch_bounds__(256, 3) void gemm_qkv(
    const unsigned short* __restrict__ A,
    const unsigned short* __restrict__ Wq,
    const unsigned short* __restrict__ Wk,
    const unsigned short* __restrict__ Wv,
    const float* __restrict__ bq,
    const float* __restrict__ bk,
    const float* __restrict__ bvp,
    unsigned short* __restrict__ Qb,
    unsigned short* __restrict__ Kfo,
    unsigned short* __restrict__ Vf)
{
    __shared__ __align__(16) unsigned short As[128 * 64];      // 16 KB
    __shared__ __align__(16) unsigned short Bs[3][64 * 64];    // 24 KB

    const int tid  = threadIdx.x;
    const int w    = tid >> 6, lane = tid & 63;
    const int quad = lane >> 4, l16 = lane & 15;
    const int wm   = w & 1,  wn = w >> 1;
    const int lane8 = lane >> 3, sc = lane & 7;
    const int m0   = blockIdx.x * 128;
    const int h    = blockIdx.y;
    const int n0   = h * 64;

    v4f acc[3][4][2];
    #pragma unroll
    for (int s = 0; s < 3; ++s)
        #pragma unroll
        for (int i = 0; i < 4; ++i)
            #pragma unroll
            for (int j = 0; j < 2; ++j)
                acc[s][i][j] = v4f{0.f, 0.f, 0.f, 0.f};

    for (int kb = 0; kb < DIM; kb += 64) {
        __syncthreads();
        #pragma unroll
        for (int t = 0; t < 4; ++t) {
            int r8 = w * 32 + t * 8;
            int r  = r8 + lane8;
            int gch = sc ^ (r & 7);
            g2l16(&A[(size_t)(m0 + r) * DIM + kb + gch * 8], &As[r8 * 64]);
        }
        #pragma unroll
        for (int u = 0; u < 6; ++u) {
            int G = w * 6 + u;               // 0..23: set = G>>3, rowgrp = G&7
            int set = G >> 3, rg = G & 7;
            int row = rg * 8 + lane8;
            int gch = sc ^ (row & 7);
            const unsigned short* Wp = (set == 0) ? Wq : (set == 1) ? Wk : Wv;
            g2l16(&Wp[(size_t)(n0 + row) * DIM + kb + gch * 8], &Bs[set][rg * 8 * 64]);
        }
        __syncthreads();
        #pragma unroll
        for (int kk = 0; kk < 64; kk += 32) {
            int chb = kk >> 3;
            v8s a[4];
            #pragma unroll
            for (int i = 0; i < 4; ++i) {
                int m = wm * 64 + i * 16 + l16;
                a[i] = *reinterpret_cast<const v8s*>(
                    &As[m * 64 + (((chb + quad) ^ (m & 7)) << 3)]);
            }
            #pragma unroll
            for (int s = 0; s < 3; ++s) {
                v8s b[2];
                #pragma unroll
                for (int j = 0; j < 2; ++j) {
                    int n = wn * 32 + j * 16 + l16;
                    b[j] = *reinterpret_cast<const v8s*>(
                        &Bs[s][n * 64 + (((chb + quad) ^ (n & 7)) << 3)]);
                }
                #pragma unroll
                for (int i = 0; i < 4; ++i)
                    #pragma unroll
                    for (int j = 0; j < 2; ++j)
                        acc[s][i][j] = __builtin_amdgcn_mfma_f32_16x16x32_bf16(
                            a[i], b[j], acc[s][i][j], 0, 0, 0);
            }
        }
    }

    // ---- epilogues ----
    // Q: [bh][seq][hd], pre-scaled by 1/8 * log2(e)
    #pragma unroll
    for (int i = 0; i < 4; ++i) {
        #pragma unroll
        for (int j = 0; j < 2; ++j) {
            int hd = wn * 32 + j * 16 + l16;
            float bias_v = bq[n0 + hd];
            #pragma unroll
            for (int r = 0; r < 4; ++r) {
                int gm = m0 + wm * 64 + i * 16 + quad * 4 + r;
                int bb = gm >> 11, sq = gm & (SEQ - 1);
                Qb[((size_t)(bb * NH + h) * SEQ + sq) * HD + hd] =
                    f2b((acc[0][i][j][r] + bias_v) * 0.1803368801f);
            }
        }
    }
    // K: fragment-native Kf[bh][t][kh*4+c][lane(=hdbit3*32 + key&31)][8]
    #pragma unroll
    for (int i = 0; i < 4; ++i) {
        int kh = i >> 1;
        #pragma unroll
        for (int j = 0; j < 2; ++j) {
            int hd = wn * 32 + j * 16 + l16;
            int c  = hd >> 4;              // = wn*2 + j
            int half_a = (l16 >> 3) & 1;   // hd bit 3
            int jj = l16 & 7;              // hd low 3 bits
            float bias_v = bk[n0 + hd];
            int gm0 = m0 + wm * 64 + i * 16 + quad * 4;
            int bb = gm0 >> 11, sk = gm0 & (SEQ - 1);
            int t = sk >> 6;
            int l31k = (i & 1) * 16 + quad * 4;          // + r below
            size_t frag = ((size_t)(bb * NH + h) * NKB + t) * 8 + kh * 4 + c;
            unsigned short* dst = &Kfo[frag * 512 + (half_a * 32 + l31k) * 8 + jj];
            #pragma unroll
            for (int r = 0; r < 4; ++r)
                dst[r * 8] = f2b(acc[1][i][j][r] + bias_v);
        }
    }
    // V: fragment-native Vf[bh][kbi][hb*4+c][lane][8]
    #pragma unroll
    for (int i = 0; i < 4; ++i) {
        #pragma unroll
        for (int j = 0; j < 2; ++j) {
            int hd = wn * 32 + j * 16 + l16;
            int hb = hd >> 5, l31v = hd & 31;
            float bias_v = bvp[n0 + hd];
            int gm0 = m0 + wm * 64 + i * 16 + quad * 4;
            int bb = gm0 >> 11, sk = gm0 & (SEQ - 1);
            int kbi = sk >> 6;
            int halfv = quad >> 1, j0 = (quad & 1) * 4;
            ushort4 pkv;
            pkv.x = f2b(acc[2][i][j][0] + bias_v);
            pkv.y = f2b(acc[2][i][j][1] + bias_v);
            pkv.z = f2b(acc[2][i][j][2] + bias_v);
            pkv.w = f2b(acc[2][i][j][3] + bias_v);
            size_t frag = ((size_t)(bb * NH + h) * NKB + kbi) * 8 + hb * 4 + i;
            *reinterpret_cast<ushort4*>(
                &Vf[frag * 512 + (halfv * 32 + l31v) * 8 + j0]) = pkv;
        }
    }
}

// Output projection: 128x64 tiles, grid (64, 12) = 768 blocks = 3 WG/CU even.
__global__ __launch_bounds__(256, 3) void gemm_o(
    const unsigned short* __restrict__ A,
    const unsigned short* __restrict__ W,
    const float* __restrict__ bias,
    float* __restrict__ out)
{
    __shared__ __align__(16) unsigned short As[128 * 64];   // 16 KB
    __shared__ __align__(16) unsigned short Bs[64 * 64];    // 8 KB

    const int tid  = threadIdx.x;
    const int w    = tid >> 6, lane = tid & 63;
    const int quad = lane >> 4, l16 = lane & 15;
    const int wm   = w & 1,  wn = w >> 1;
    const int lane8 = lane >> 3, sc = lane & 7;
    const int m0  = blockIdx.x * 128;
    const int n0l = blockIdx.y * 64;

    v4f acc[4][2];
    #pragma unroll
    for (int i = 0; i < 4; ++i)
        #pragma unroll
        for (int j = 0; j < 2; ++j)
            acc[i][j] = v4f{0.f, 0.f, 0.f, 0.f};

    for (int kb = 0; kb < DIM; kb += 64) {
        __syncthreads();
        #pragma unroll
        for (int t = 0; t < 4; ++t) {
            int r8 = w * 32 + t * 8;
            int r  = r8 + lane8;
            int gch = sc ^ (r & 7);
            g2l16(&A[(size_t)(m0 + r) * DIM + kb + gch * 8], &As[r8 * 64]);
        }
        #pragma unroll
        for (int t = 0; t < 2; ++t) {
            int r8 = (w * 2 + t) * 8;
            int r  = r8 + lane8;
            int gch = sc ^ (r & 7);
            g2l16(&W[(size_t)(n0l + r) * DIM + kb + gch * 8], &Bs[r8 * 64]);
        }
        __syncthreads();
        #pragma unroll
        for (int kk = 0; kk < 64; kk += 32) {
            v8s a[4], b[2];
            int chb = kk >> 3;
            #pragma unroll
            for (int i = 0; i < 4; ++i) {
                int m = wm * 64 + i * 16 + l16;
                a[i] = *reinterpret_cast<const v8s*>(
                    &As[m * 64 + (((chb + quad) ^ (m & 7)) << 3)]);
            }
            #pragma unroll
            for (int j = 0; j < 2; ++j) {
                int n = wn * 32 + j * 16 + l16;
                b[j] = *reinterpret_cast<const v8s*>(
                    &Bs[n * 64 + (((chb + quad) ^ (n & 7)) << 3)]);
            }
            #pragma unroll
            for (int i = 0; i < 4; ++i)
                #pragma unroll
                for (int j = 0; j < 2; ++j)
                    acc[i][j] = __builtin_amdgcn_mfma_f32_16x16x32_bf16(a[i], b[j], acc[i][j], 0, 0, 0);
        }
    }

    #pragma unroll
    for (int i = 0; i < 4; ++i) {
        #pragma unroll
        for (int j = 0; j < 2; ++j) {
            int gn = n0l + wn * 32 + j * 16 + l16;
            float bias_v = bias[gn];
            #pragma unroll
            for (int r = 0; r < 4; ++r) {
                int gm = m0 + wm * 64 + i * 16 + quad * 4 + r;
                out[(size_t)gm * DIM + gn] = acc[i][j][r] + bias_v;
            }
        }
    }
}

// ---------------------------------------------------------------------------
// Transposed flash attention, R2: LDS-shared K (fragment-native, linear DMA +
// linear conflict-free ds_read_b128), raw s_barrier with COUNTED vmcnt(8)
// (never 0: the 8 newest outstanding VMEM ops are always the V prefetch, the
// 2 K-DMA ops sit below them), V register-double-buffered 2 tiles ahead,
// XCD-swizzled blockIdx so each XCD's resident blocks share 6 bh (3MB < L2).
// ---------------------------------------------------------------------------
static __device__ __forceinline__ void tile_step(
    int it, int buf,
    const unsigned short* __restrict__ Kh,
    const unsigned short* __restrict__ Vh,
    unsigned short (&Ks)[2][8 * 512],
    int w, int lane, int half,
    const v8s (&bq)[4], v8s (&VA)[2][4],
    v16f& o0, v16f& o1, const v16f& Z, float& li)
{
    // certify K(it) across all waves WITHOUT draining the V prefetch:
    // outstanding (old->new): V(it)x8, K(it)x2, V(it+1)x8  -> vmcnt(8)
    asm volatile("s_waitcnt vmcnt(8)" ::: "memory");
    __builtin_amdgcn_s_barrier();
    __builtin_amdgcn_sched_barrier(0);

    // K-DMA for tile it+1 (2 frags per wave); pin so V loads can't hoist above
    {
        int nt = (it + 1 < NKB) ? it + 1 : it;
        #pragma unroll
        for (int t = 0; t < 2; ++t) {
            int g = w * 2 + t;
            g2l16(&Kh[((size_t)nt * 8 + g) * 512 + lane * 8], &Ks[buf ^ 1][g * 512]);
        }
    }
    __builtin_amdgcn_sched_barrier(0);

    // S^T[key][q]: two independent 4-deep MFMA chains (keys 0..31 / 32..63)
    const unsigned short* Kb_ = Ks[buf];
    v16f s0, s1;
    {
        v8s k0 = *reinterpret_cast<const v8s*>(&Kb_[lane * 8]);
        v8s k1 = *reinterpret_cast<const v8s*>(&Kb_[4 * 512 + lane * 8]);
        s0 = __builtin_amdgcn_mfma_f32_32x32x16_bf16(k0, bq[0], Z, 0, 0, 0);
        s1 = __builtin_amdgcn_mfma_f32_32x32x16_bf16(k1, bq[0], Z, 0, 0, 0);
        #pragma unroll
        for (int c = 1; c < 4; ++c) {
            v8s kc0 = *reinterpret_cast<const v8s*>(&Kb_[(size_t)c * 512 + lane * 8]);
            v8s kc1 = *reinterpret_cast<const v8s*>(&Kb_[(size_t)(4 + c) * 512 + lane * 8]);
            s0 = __builtin_amdgcn_mfma_f32_32x32x16_bf16(kc0, bq[c], s0, 0, 0, 0);
            s1 = __builtin_amdgcn_mfma_f32_32x32x16_bf16(kc1, bq[c], s1, 0, 0, 0);
        }
    }

    // exp2 + lane-local li + pack key-pairs (1 instr per pair via cvt_pk)
    unsigned pk[8][2];
    #pragma unroll
    for (int g = 0; g < 4; ++g) {
        float e0 = EXP2(s0[4*g+0]), e1 = EXP2(s0[4*g+1]);
        float e2 = EXP2(s0[4*g+2]), e3 = EXP2(s0[4*g+3]);
        li += (e0 + e1) + (e2 + e3);
        pk[g][0] = cvtpk(e0, e1);
        pk[g][1] = cvtpk(e2, e3);
        float f0 = EXP2(s1[4*g+0]), f1 = EXP2(s1[4*g+1]);
        float f2 = EXP2(s1[4*g+2]), f3 = EXP2(s1[4*g+3]);
        li += (f0 + f1) + (f2 + f3);
        pk[4+g][0] = cvtpk(f0, f1);
        pk[4+g][1] = cvtpk(f2, f3);
    }

    // P^T B-frags: partner (lane^32) holds the complementary 4-key blocks.
    #pragma unroll
    for (int cp = 0; cp < 4; ++cp) {
        unsigned a0 = pk[2*cp][0],   a1 = pk[2*cp][1];
        unsigned b0 = pk[2*cp+1][0], b1 = pk[2*cp+1][1];
        unsigned u0 = half ? a0 : b0;      // what my partner needs from me
        unsigned u1 = half ? a1 : b1;
        unsigned x0 = __shfl_xor(u0, 32);
        unsigned x1 = __shfl_xor(u1, 32);
        v4u fw;
        fw.x = half ? x0 : a0;
        fw.y = half ? x1 : a1;
        fw.z = half ? b0 : x0;
        fw.w = half ? b1 : x1;
        v8s pf = __builtin_bit_cast(v8s, fw);
        o0 = __builtin_amdgcn_mfma_f32_32x32x16_bf16(VA[0][cp], pf, o0, 0, 0, 0);
        o1 = __builtin_amdgcn_mfma_f32_32x32x16_bf16(VA[1][cp], pf, o1, 0, 0, 0);
    }

    // V prefetch 2 tiles ahead into the buffer PV just released (always 8 ops)
    {
        int ntv = (it + 2 < NKB) ? it + 2 : it;
        #pragma unroll
        for (int g = 0; g < 8; ++g)
            reinterpret_cast<v8s*>(VA)[g] =
                *reinterpret_cast<const v8s*>(&Vh[((size_t)ntv * 8 + g) * 512]);
    }
}

__global__ __launch_bounds__(256, 3) void attn(
    const unsigned short* __restrict__ Q,
    const unsigned short* __restrict__ Kf,
    const unsigned short* __restrict__ Vf,
    unsigned short* __restrict__ ctx)
{
    __shared__ __align__(16) unsigned short Ks[2][8 * 512];   // 16 KB

    const int tid  = threadIdx.x;
    const int w    = tid >> 6, lane = tid & 63;
    const int l31  = lane & 31, half = lane >> 5;

    // XCD swizzle: 768 blocks, 8 XCDs -> XCD k owns bh [6k, 6k+6) x 16 q-tiles
    const int lblk = blockIdx.y * 16 + blockIdx.x;       // gridDim.x == 16
    const int vblk = (lblk & 7) * 96 + (lblk >> 3);
    const int bh   = vblk >> 4;
    const int b    = bh / NH, h = bh % NH;
    const int q0   = (vblk & 15) * 128 + w * 32;

    const unsigned short* Qp = Q  + ((size_t)bh * SEQ + q0) * HD;
    const unsigned short* Vh = Vf + (size_t)bh * (NKB * 8 * 512) + lane * 8;
    const unsigned short* Kh = Kf + (size_t)bh * (NKB * 8 * 512);

    // Q B-frag: B[n=q=l31][k = c*16 + half*8 + j] (pre-scaled by 0.125*log2e)
    v8s bq[4];
    #pragma unroll
    for (int c = 0; c < 4; ++c)
        bq[c] = *reinterpret_cast<const v8s*>(&Qp[l31 * HD + c * 16 + half * 8]);

    // prologue: K-DMA first (so it's older than all V prefetches), then V(0),V(1)
    #pragma unroll
    for (int t = 0; t < 2; ++t) {
        int g = w * 2 + t;
        g2l16(&Kh[(size_t)g * 512 + lane * 8], &Ks[0][g * 512]);
    }
    __builtin_amdgcn_sched_barrier(0);

    v8s vaA[2][4], vaB[2][4];
    #pragma unroll
    for (int g = 0; g < 8; ++g)
        reinterpret_cast<v8s*>(vaA)[g] = *reinterpret_cast<const v8s*>(&Vh[(size_t)g * 512]);
    #pragma unroll
    for (int g = 0; g < 8; ++g)
        reinterpret_cast<v8s*>(vaB)[g] = *reinterpret_cast<const v8s*>(&Vh[(size_t)(8 + g) * 512]);

    v16f o0, o1, Z;
    #pragma unroll
    for (int i = 0; i < 16; ++i) { o0[i] = 0.f; o1[i] = 0.f; Z[i] = 0.f; }
    float li = 0.f;

    // manual 2x unroll: static register-buffer selection (rule #20)
    for (int it = 0; it < NKB; it += 2) {
        tile_step(it,     0, Kh, Vh, Ks, w, lane, half, bq, vaA, o0, o1, Z, li);
        tile_step(it + 1, 1, Kh, Vh, Ks, w, lane, half, bq, vaB, o0, o1, Z, li);
    }

    // li total = own 32 keys + partner's 32 keys (same q)
    float inv = 1.0f / (li + __shfl_xor(li, 32));

    // O^T: lane holds q = q0+l31; rows hd = (reg&3)+8*(reg>>2)+4*half (+32 for o1)
    const int q = q0 + l31;
    size_t base = ((size_t)(b * SEQ + q)) * DIM + h * HD;
    #pragma unroll
    for (int g = 0; g < 4; ++g) {
        int hd0 = 8 * g + 4 * half;
        uint2 u0, u1;
        u0.x = cvtpk(o0[4*g+0] * inv, o0[4*g+1] * inv);
        u0.y = cvtpk(o0[4*g+2] * inv, o0[4*g+3] * inv);
        u1.x = cvtpk(o1[4*g+0] * inv, o1[4*g+1] * inv);
        u1.y = cvtpk(o1[4*g+2] * inv, o1[4*g+3] * inv);
        *reinterpret_cast<uint2*>(&ctx[base + hd0])      = u0;
        *reinterpret_cast<uint2*>(&ctx[base + 32 + hd0]) = u1;
    }
}

extern "C" void kernel_launch(void* const* d_in, const int* in_sizes, int n_in,
                              void* d_out, int out_size, void* d_ws, size_t ws_size,
                              hipStream_t stream) {
    const float* x  = (const float*)d_in[0];
    const float* qw = (const float*)d_in[1]; const float* qb = (const float*)d_in[2];
    const float* kw = (const float*)d_in[3]; const float* kb = (const float*)d_in[4];
    const float* vw = (const float*)d_in[5]; const float* vb = (const float*)d_in[6];
    const float* ow = (const float*)d_in[7]; const float* ob = (const float*)d_in[8];
    float* out = (float*)d_out;

    char* ws = (char*)d_ws;
    size_t off = 0;
    auto alloc = [&](size_t bytes) -> unsigned short* {
        unsigned short* p = (unsigned short*)(ws + off);
        off += (bytes + 255) & ~(size_t)255;
        return p;
    };
    const size_t XB = (size_t)MM * DIM * 2;
    const size_t WB = (size_t)DIM * DIM * 2;
    const size_t QB = (size_t)NB * NH * SEQ * HD * 2;

    unsigned short* xb  = alloc(XB);
    unsigned short* wqb = alloc(WB);
    unsigned short* wkb = alloc(WB);
    unsigned short* wvb = alloc(WB);
    unsigned short* wob = alloc(WB);
    unsigned short* Qb  = alloc(QB);
    unsigned short* Kfb = alloc(QB);   // fragment-native K
    unsigned short* Vfb = alloc(QB);   // fragment-native V
    unsigned short* ctx = alloc(XB);

    const int n4x = MM * DIM / 4;
    const int n4w = DIM * DIM / 4;
    cast_f32_bf16<<<(n4x + 255) / 256, 256, 0, stream>>>(x, xb, n4x);
    cast4_f32_bf16<<<dim3((n4w + 255) / 256, 4), 256, 0, stream>>>(
        qw, kw, vw, ow, wqb, wkb, wvb, wob, n4w);

    gemm_qkv<<<dim3(MM / 128, NH), 256, 0, stream>>>(
        xb, wqb, wkb, wvb, qb, kb, vb, Qb, Kfb, Vfb);

    attn<<<dim3(SEQ / 128, NB * NH), 256, 0, stream>>>(Qb, Kfb, Vfb, ctx);

    gemm_o<<<dim3(MM / 128, DIM / 64), 256, 0, stream>>>(ctx, wob, ob, out);
}

// Round 5
// 209.911 us; speedup vs baseline: 1.1507x; 1.0059x over previous
//
#include <hip/hip_runtime.h>
#include <hip/hip_bf16.h>

#define NH  12
#define HD  64
#define DIM 768
#define SEQ 2048
#define NB  4
#define MM  (NB*SEQ)   // 8192 rows
#define NKB (SEQ/64)   // 32 key-blocks per head

typedef short    v8s  __attribute__((ext_vector_type(8)));   // 8 x bf16 (4 VGPRs)
typedef float    v4f  __attribute__((ext_vector_type(4)));
typedef float    v16f __attribute__((ext_vector_type(16)));
typedef unsigned v4u  __attribute__((ext_vector_type(4)));

#if __has_builtin(__builtin_amdgcn_exp2f)
#define EXP2(x) __builtin_amdgcn_exp2f(x)
#else
#define EXP2(x) __builtin_exp2f(x)
#endif

// round-to-nearest-even f32 -> bf16
static __device__ __forceinline__ unsigned short f2b(float f) {
    unsigned int u = __float_as_uint(f);
    return (unsigned short)((u + 0x7FFFu + ((u >> 16) & 1u)) >> 16);
}
// single-instruction pack: dst = bf16(lo) | bf16(hi)<<16 (RNE)
static __device__ __forceinline__ unsigned cvtpk(float lo, float hi) {
    unsigned r;
    asm("v_cvt_pk_bf16_f32 %0, %1, %2" : "=v"(r) : "v"(lo), "v"(hi));
    return r;
}
// async global->LDS DMA, 16B/lane; LDS base wave-uniform, writes base+lane*16
static __device__ __forceinline__ void g2l16(const unsigned short* g, unsigned short* l) {
    __builtin_amdgcn_global_load_lds(
        (const __attribute__((address_space(1))) void*)g,
        (__attribute__((address_space(3))) void*)l, 16, 0, 0);
}

__global__ void cast_f32_bf16(const float* __restrict__ in,
                              unsigned short* __restrict__ out, int n4) {
    int i = blockIdx.x * blockDim.x + threadIdx.x;
    if (i < n4) {
        float4 v = reinterpret_cast<const float4*>(in)[i];
        ushort4 o;
        o.x = f2b(v.x); o.y = f2b(v.y); o.z = f2b(v.z); o.w = f2b(v.w);
        reinterpret_cast<ushort4*>(out)[i] = o;
    }
}

__global__ void cast4_f32_bf16(const float* __restrict__ i0, const float* __restrict__ i1,
                               const float* __restrict__ i2, const float* __restrict__ i3,
                               unsigned short* __restrict__ o0, unsigned short* __restrict__ o1,
                               unsigned short* __restrict__ o2, unsigned short* __restrict__ o3,
                               int n4) {
    int i = blockIdx.x * blockDim.x + threadIdx.x;
    if (i >= n4) return;
    const float* in; unsigned short* out;
    switch (blockIdx.y) {
        case 0: in = i0; out = o0; break;
        case 1: in = i1; out = o1; break;
        case 2: in = i2; out = o2; break;
        default: in = i3; out = o3; break;
    }
    float4 v = reinterpret_cast<const float4*>(in)[i];
    ushort4 o;
    o.x = f2b(v.x); o.y = f2b(v.y); o.z = f2b(v.z); o.w = f2b(v.w);
    reinterpret_cast<ushort4*>(out)[i] = o;
}

// Merged QKV: grid (MM/128, NH). One block computes Q,K,V for 128 rows x one
// head (64 features). K and V written FRAGMENT-NATIVE (MFMA A-frag layout):
// attn streams both as coalesced per-wave register frags from L2.
__global__ __launch_bounds__(256, 3) void gemm_qkv(
    const unsigned short* __restrict__ A,
    const unsigned short* __restrict__ Wq,
    const unsigned short* __restrict__ Wk,
    const unsigned short* __restrict__ Wv,
    const float* __restrict__ bq,
    const float* __restrict__ bk,
    const float* __restrict__ bvp,
    unsigned short* __restrict__ Qb,
    unsigned short* __restrict__ Kfo,
    unsigned short* __restrict__ Vf)
{
    __shared__ __align__(16) unsigned short As[128 * 64];      // 16 KB
    __shared__ __align__(16) unsigned short Bs[3][64 * 64];    // 24 KB

    const int tid  = threadIdx.x;
    const int w    = tid >> 6, lane = tid & 63;
    const int quad = lane >> 4, l16 = lane & 15;
    const int wm   = w & 1,  wn = w >> 1;
    const int lane8 = lane >> 3, sc = lane & 7;
    const int m0   = blockIdx.x * 128;
    const int h    = blockIdx.y;
    const int n0   = h * 64;

    v4f acc[3][4][2];
    #pragma unroll
    for (int s = 0; s < 3; ++s)
        #pragma unroll
        for (int i = 0; i < 4; ++i)
            #pragma unroll
            for (int j = 0; j < 2; ++j)
                acc[s][i][j] = v4f{0.f, 0.f, 0.f, 0.f};

    for (int kb = 0; kb < DIM; kb += 64) {
        __syncthreads();
        #pragma unroll
        for (int t = 0; t < 4; ++t) {
            int r8 = w * 32 + t * 8;
            int r  = r8 + lane8;
            int gch = sc ^ (r & 7);
            g2l16(&A[(size_t)(m0 + r) * DIM + kb + gch * 8], &As[r8 * 64]);
        }
        #pragma unroll
        for (int u = 0; u < 6; ++u) {
            int G = w * 6 + u;               // 0..23: set = G>>3, rowgrp = G&7
            int set = G >> 3, rg = G & 7;
            int row = rg * 8 + lane8;
            int gch = sc ^ (row & 7);
            const unsigned short* Wp = (set == 0) ? Wq : (set == 1) ? Wk : Wv;
            g2l16(&Wp[(size_t)(n0 + row) * DIM + kb + gch * 8], &Bs[set][rg * 8 * 64]);
        }
        __syncthreads();
        #pragma unroll
        for (int kk = 0; kk < 64; kk += 32) {
            int chb = kk >> 3;
            v8s a[4];
            #pragma unroll
            for (int i = 0; i < 4; ++i) {
                int m = wm * 64 + i * 16 + l16;
                a[i] = *reinterpret_cast<const v8s*>(
                    &As[m * 64 + (((chb + quad) ^ (m & 7)) << 3)]);
            }
            #pragma unroll
            for (int s = 0; s < 3; ++s) {
                v8s b[2];
                #pragma unroll
                for (int j = 0; j < 2; ++j) {
                    int n = wn * 32 + j * 16 + l16;
                    b[j] = *reinterpret_cast<const v8s*>(
                        &Bs[s][n * 64 + (((chb + quad) ^ (n & 7)) << 3)]);
                }
                #pragma unroll
                for (int i = 0; i < 4; ++i)
                    #pragma unroll
                    for (int j = 0; j < 2; ++j)
                        acc[s][i][j] = __builtin_amdgcn_mfma_f32_16x16x32_bf16(
                            a[i], b[j], acc[s][i][j], 0, 0, 0);
            }
        }
    }

    // ---- epilogues ----
    // Q: [bh][seq][hd], pre-scaled by 1/8 * log2(e)
    #pragma unroll
    for (int i = 0; i < 4; ++i) {
        #pragma unroll
        for (int j = 0; j < 2; ++j) {
            int hd = wn * 32 + j * 16 + l16;
            float bias_v = bq[n0 + hd];
            #pragma unroll
            for (int r = 0; r < 4; ++r) {
                int gm = m0 + wm * 64 + i * 16 + quad * 4 + r;
                int bb = gm >> 11, sq = gm & (SEQ - 1);
                Qb[((size_t)(bb * NH + h) * SEQ + sq) * HD + hd] =
                    f2b((acc[0][i][j][r] + bias_v) * 0.1803368801f);
            }
        }
    }
    // K: fragment-native Kf[bh][t][kh*4+c][lane(=hdbit3*32 + key&31)][8]
    #pragma unroll
    for (int i = 0; i < 4; ++i) {
        int kh = i >> 1;
        #pragma unroll
        for (int j = 0; j < 2; ++j) {
            int hd = wn * 32 + j * 16 + l16;
            int c  = hd >> 4;              // = wn*2 + j
            int half_a = (l16 >> 3) & 1;   // hd bit 3
            int jj = l16 & 7;              // hd low 3 bits
            float bias_v = bk[n0 + hd];
            int gm0 = m0 + wm * 64 + i * 16 + quad * 4;
            int bb = gm0 >> 11, sk = gm0 & (SEQ - 1);
            int t = sk >> 6;
            int l31k = (i & 1) * 16 + quad * 4;          // + r below
            size_t frag = ((size_t)(bb * NH + h) * NKB + t) * 8 + kh * 4 + c;
            unsigned short* dst = &Kfo[frag * 512 + (half_a * 32 + l31k) * 8 + jj];
            #pragma unroll
            for (int r = 0; r < 4; ++r)
                dst[r * 8] = f2b(acc[1][i][j][r] + bias_v);
        }
    }
    // V: fragment-native Vf[bh][kbi][hb*4+c][lane][8]
    #pragma unroll
    for (int i = 0; i < 4; ++i) {
        #pragma unroll
        for (int j = 0; j < 2; ++j) {
            int hd = wn * 32 + j * 16 + l16;
            int hb = hd >> 5, l31v = hd & 31;
            float bias_v = bvp[n0 + hd];
            int gm0 = m0 + wm * 64 + i * 16 + quad * 4;
            int bb = gm0 >> 11, sk = gm0 & (SEQ - 1);
            int kbi = sk >> 6;
            int halfv = quad >> 1, j0 = (quad & 1) * 4;
            ushort4 pkv;
            pkv.x = f2b(acc[2][i][j][0] + bias_v);
            pkv.y = f2b(acc[2][i][j][1] + bias_v);
            pkv.z = f2b(acc[2][i][j][2] + bias_v);
            pkv.w = f2b(acc[2][i][j][3] + bias_v);
            size_t frag = ((size_t)(bb * NH + h) * NKB + kbi) * 8 + hb * 4 + i;
            *reinterpret_cast<ushort4*>(
                &Vf[frag * 512 + (halfv * 32 + l31v) * 8 + j0]) = pkv;
        }
    }
}

// Output projection: 128x64 tiles, grid (64, 12) = 768 blocks = 3 WG/CU even.
__global__ __launch_bounds__(256, 3) void gemm_o(
    const unsigned short* __restrict__ A,
    const unsigned short* __restrict__ W,
    const float* __restrict__ bias,
    float* __restrict__ out)
{
    __shared__ __align__(16) unsigned short As[128 * 64];   // 16 KB
    __shared__ __align__(16) unsigned short Bs[64 * 64];    // 8 KB

    const int tid  = threadIdx.x;
    const int w    = tid >> 6, lane = tid & 63;
    const int quad = lane >> 4, l16 = lane & 15;
    const int wm   = w & 1,  wn = w >> 1;
    const int lane8 = lane >> 3, sc = lane & 7;
    const int m0  = blockIdx.x * 128;
    const int n0l = blockIdx.y * 64;

    v4f acc[4][2];
    #pragma unroll
    for (int i = 0; i < 4; ++i)
        #pragma unroll
        for (int j = 0; j < 2; ++j)
            acc[i][j] = v4f{0.f, 0.f, 0.f, 0.f};

    for (int kb = 0; kb < DIM; kb += 64) {
        __syncthreads();
        #pragma unroll
        for (int t = 0; t < 4; ++t) {
            int r8 = w * 32 + t * 8;
            int r  = r8 + lane8;
            int gch = sc ^ (r & 7);
            g2l16(&A[(size_t)(m0 + r) * DIM + kb + gch * 8], &As[r8 * 64]);
        }
        #pragma unroll
        for (int t = 0; t < 2; ++t) {
            int r8 = (w * 2 + t) * 8;
            int r  = r8 + lane8;
            int gch = sc ^ (r & 7);
            g2l16(&W[(size_t)(n0l + r) * DIM + kb + gch * 8], &Bs[r8 * 64]);
        }
        __syncthreads();
        #pragma unroll
        for (int kk = 0; kk < 64; kk += 32) {
            v8s a[4], b[2];
            int chb = kk >> 3;
            #pragma unroll
            for (int i = 0; i < 4; ++i) {
                int m = wm * 64 + i * 16 + l16;
                a[i] = *reinterpret_cast<const v8s*>(
                    &As[m * 64 + (((chb + quad) ^ (m & 7)) << 3)]);
            }
            #pragma unroll
            for (int j = 0; j < 2; ++j) {
                int n = wn * 32 + j * 16 + l16;
                b[j] = *reinterpret_cast<const v8s*>(
                    &Bs[n * 64 + (((chb + quad) ^ (n & 7)) << 3)]);
            }
            #pragma unroll
            for (int i = 0; i < 4; ++i)
                #pragma unroll
                for (int j = 0; j < 2; ++j)
                    acc[i][j] = __builtin_amdgcn_mfma_f32_16x16x32_bf16(a[i], b[j], acc[i][j], 0, 0, 0);
        }
    }

    #pragma unroll
    for (int i = 0; i < 4; ++i) {
        #pragma unroll
        for (int j = 0; j < 2; ++j) {
            int gn = n0l + wn * 32 + j * 16 + l16;
            float bias_v = bias[gn];
            #pragma unroll
            for (int r = 0; r < 4; ++r) {
                int gm = m0 + wm * 64 + i * 16 + quad * 4 + r;
                out[(size_t)gm * DIM + gn] = acc[i][j][r] + bias_v;
            }
        }
    }
}

// ---------------------------------------------------------------------------
// Transposed flash attention, R4: ZERO LDS / ZERO BARRIERS + XCD swizzle,
// NO scheduling hints. This is exactly R1's verified kernel body (passed,
// absmax 4.88e-4) plus R2's verified swizzle (passed, 4.88e-4). R3 added
// s_setprio + sched_barrier(0) and failed numerically -> those hints are
// the only unverified delta and are removed (suspected codegen/hazard
// perturbation around the inline-asm cvtpk + MFMA register reuse).
// Swizzle keeps each XCD's K/V working set at 6 bh x 512 KB = 3 MB < L2,
// and all 96 blocks of an XCD are co-resident (3 blk/CU x 32 CU), so the
// per-wave register streams hit L2 (~200-300 cy) under ~500 cy of prefetch
// distance. Free-running waves de-phase -> exp2 of one wave overlaps MFMA
// of another without any explicit arbitration.
// ---------------------------------------------------------------------------
__global__ __launch_bounds__(256, 3) void attn(
    const unsigned short* __restrict__ Q,
    const unsigned short* __restrict__ Kf,
    const unsigned short* __restrict__ Vf,
    unsigned short* __restrict__ ctx)
{
    const int tid  = threadIdx.x;
    const int w    = tid >> 6, lane = tid & 63;
    const int l31  = lane & 31, half = lane >> 5;

    // XCD swizzle: 768 blocks, 8 XCDs -> XCD k owns bh [6k, 6k+6) x 16 q-tiles
    const int lblk = blockIdx.y * 16 + blockIdx.x;       // gridDim.x == 16
    const int vblk = (lblk & 7) * 96 + (lblk >> 3);
    const int bh   = vblk >> 4;
    const int b    = bh / NH, h = bh % NH;
    const int q0   = (vblk & 15) * 128 + w * 32;

    const unsigned short* Qp = Q  + ((size_t)bh * SEQ + q0) * HD;
    const unsigned short* Kh = Kf + (size_t)bh * (NKB * 8 * 512) + lane * 8;
    const unsigned short* Vh = Vf + (size_t)bh * (NKB * 8 * 512) + lane * 8;

    // Q B-frag: B[n=q=l31][k = c*16 + half*8 + j] (pre-scaled by 0.125*log2e)
    v8s bq[4];
    #pragma unroll
    for (int c = 0; c < 4; ++c)
        bq[c] = *reinterpret_cast<const v8s*>(&Qp[l31 * HD + c * 16 + half * 8]);

    // K/V A-frags for tile 0 (coalesced: consecutive lanes -> consecutive 16B)
    v8s ka[2][4], va[2][4];
    #pragma unroll
    for (int g = 0; g < 8; ++g)
        reinterpret_cast<v8s*>(ka)[g] = *reinterpret_cast<const v8s*>(&Kh[(size_t)g * 512]);
    #pragma unroll
    for (int g = 0; g < 8; ++g)
        reinterpret_cast<v8s*>(va)[g] = *reinterpret_cast<const v8s*>(&Vh[(size_t)g * 512]);

    v16f o0, o1, Z;
    #pragma unroll
    for (int i = 0; i < 16; ++i) { o0[i] = 0.f; o1[i] = 0.f; Z[i] = 0.f; }
    float li = 0.f;

    for (int it = 0; it < NKB; ++it) {
        // S^T[key][q]: two independent 4-deep MFMA chains (keys 0..31 / 32..63)
        v16f s0 = __builtin_amdgcn_mfma_f32_32x32x16_bf16(ka[0][0], bq[0], Z, 0, 0, 0);
        v16f s1 = __builtin_amdgcn_mfma_f32_32x32x16_bf16(ka[1][0], bq[0], Z, 0, 0, 0);
        #pragma unroll
        for (int c = 1; c < 4; ++c) {
            s0 = __builtin_amdgcn_mfma_f32_32x32x16_bf16(ka[0][c], bq[c], s0, 0, 0, 0);
            s1 = __builtin_amdgcn_mfma_f32_32x32x16_bf16(ka[1][c], bq[c], s1, 0, 0, 0);
        }

        // prefetch next K tile into ka; its ~L2 latency hides under
        // exp/pack/shuffle + PV (~600 cy)
        {
            int nt = (it + 1 < NKB) ? it + 1 : it;
            #pragma unroll
            for (int g = 0; g < 8; ++g)
                reinterpret_cast<v8s*>(ka)[g] =
                    *reinterpret_cast<const v8s*>(&Kh[((size_t)nt * 8 + g) * 512]);
        }

        // exp2 + lane-local li + pack key-pairs (1 instr per pair via cvt_pk)
        unsigned pk[8][2];
        #pragma unroll
        for (int g = 0; g < 4; ++g) {
            float e0 = EXP2(s0[4*g+0]), e1 = EXP2(s0[4*g+1]);
            float e2 = EXP2(s0[4*g+2]), e3 = EXP2(s0[4*g+3]);
            li += (e0 + e1) + (e2 + e3);
            pk[g][0] = cvtpk(e0, e1);
            pk[g][1] = cvtpk(e2, e3);
            float f0 = EXP2(s1[4*g+0]), f1 = EXP2(s1[4*g+1]);
            float f2 = EXP2(s1[4*g+2]), f3 = EXP2(s1[4*g+3]);
            li += (f0 + f1) + (f2 + f3);
            pk[4+g][0] = cvtpk(f0, f1);
            pk[4+g][1] = cvtpk(f2, f3);
        }

        // P^T B-frags: partner (lane^32) holds the complementary 4-key blocks.
        #pragma unroll
        for (int cp = 0; cp < 4; ++cp) {
            unsigned a0 = pk[2*cp][0],   a1 = pk[2*cp][1];
            unsigned b0 = pk[2*cp+1][0], b1 = pk[2*cp+1][1];
            unsigned u0 = half ? a0 : b0;      // what my partner needs from me
            unsigned u1 = half ? a1 : b1;
            unsigned x0 = __shfl_xor(u0, 32);
            unsigned x1 = __shfl_xor(u1, 32);
            v4u fw;
            fw.x = half ? x0 : a0;
            fw.y = half ? x1 : a1;
            fw.z = half ? b0 : x0;
            fw.w = half ? b1 : x1;
            v8s pf = __builtin_bit_cast(v8s, fw);
            o0 = __builtin_amdgcn_mfma_f32_32x32x16_bf16(va[0][cp], pf, o0, 0, 0, 0);
            o1 = __builtin_amdgcn_mfma_f32_32x32x16_bf16(va[1][cp], pf, o1, 0, 0, 0);
        }

        // prefetch next V tile (lands during next tile's QK^T + softmax)
        {
            int nt = (it + 1 < NKB) ? it + 1 : it;
            #pragma unroll
            for (int g = 0; g < 8; ++g)
                reinterpret_cast<v8s*>(va)[g] =
                    *reinterpret_cast<const v8s*>(&Vh[((size_t)nt * 8 + g) * 512]);
        }
    }

    // li total = own 32 keys + partner's 32 keys (same q)
    float inv = 1.0f / (li + __shfl_xor(li, 32));

    // O^T: lane holds q = q0+l31; rows hd = (reg&3)+8*(reg>>2)+4*half (+32 for o1)
    const int q = q0 + l31;
    size_t base = ((size_t)(b * SEQ + q)) * DIM + h * HD;
    #pragma unroll
    for (int g = 0; g < 4; ++g) {
        int hd0 = 8 * g + 4 * half;
        uint2 u0, u1;
        u0.x = cvtpk(o0[4*g+0] * inv, o0[4*g+1] * inv);
        u0.y = cvtpk(o0[4*g+2] * inv, o0[4*g+3] * inv);
        u1.x = cvtpk(o1[4*g+0] * inv, o1[4*g+1] * inv);
        u1.y = cvtpk(o1[4*g+2] * inv, o1[4*g+3] * inv);
        *reinterpret_cast<uint2*>(&ctx[base + hd0])      = u0;
        *reinterpret_cast<uint2*>(&ctx[base + 32 + hd0]) = u1;
    }
}

extern "C" void kernel_launch(void* const* d_in, const int* in_sizes, int n_in,
                              void* d_out, int out_size, void* d_ws, size_t ws_size,
                              hipStream_t stream) {
    const float* x  = (const float*)d_in[0];
    const float* qw = (const float*)d_in[1]; const float* qb = (const float*)d_in[2];
    const float* kw = (const float*)d_in[3]; const float* kb = (const float*)d_in[4];
    const float* vw = (const float*)d_in[5]; const float* vb = (const float*)d_in[6];
    const float* ow = (const float*)d_in[7]; const float* ob = (const float*)d_in[8];
    float* out = (float*)d_out;

    char* ws = (char*)d_ws;
    size_t off = 0;
    auto alloc = [&](size_t bytes) -> unsigned short* {
        unsigned short* p = (unsigned short*)(ws + off);
        off += (bytes + 255) & ~(size_t)255;
        return p;
    };
    const size_t XB = (size_t)MM * DIM * 2;
    const size_t WB = (size_t)DIM * DIM * 2;
    const size_t QB = (size_t)NB * NH * SEQ * HD * 2;

    unsigned short* xb  = alloc(XB);
    unsigned short* wqb = alloc(WB);
    unsigned short* wkb = alloc(WB);
    unsigned short* wvb = alloc(WB);
    unsigned short* wob = alloc(WB);
    unsigned short* Qb  = alloc(QB);
    unsigned short* Kfb = alloc(QB);   // fragment-native K
    unsigned short* Vfb = alloc(QB);   // fragment-native V
    unsigned short* ctx = alloc(XB);

    const int n4x = MM * DIM / 4;
    const int n4w = DIM * DIM / 4;
    cast_f32_bf16<<<(n4x + 255) / 256, 256, 0, stream>>>(x, xb, n4x);
    cast4_f32_bf16<<<dim3((n4w + 255) / 256, 4), 256, 0, stream>>>(
        qw, kw, vw, ow, wqb, wkb, wvb, wob, n4w);

    gemm_qkv<<<dim3(MM / 128, NH), 256, 0, stream>>>(
        xb, wqb, wkb, wvb, qb, kb, vb, Qb, Kfb, Vfb);

    attn<<<dim3(SEQ / 128, NB * NH), 256, 0, stream>>>(Qb, Kfb, Vfb, ctx);

    gemm_o<<<dim3(MM / 128, DIM / 64), 256, 0, stream>>>(ctx, wob, ob, out);
}

// Round 8
// 207.518 us; speedup vs baseline: 1.1639x; 1.0115x over previous
//
#include <hip/hip_runtime.h>
#include <hip/hip_bf16.h>

#define NH  12
#define HD  64
#define DIM 768
#define SEQ 2048
#define NB  4
#define MM  (NB*SEQ)   // 8192 rows
#define NKB (SEQ/64)   // 32 key-blocks per head

typedef short    v8s  __attribute__((ext_vector_type(8)));   // 8 x bf16 (4 VGPRs)
typedef float    v4f  __attribute__((ext_vector_type(4)));
typedef float    v16f __attribute__((ext_vector_type(16)));
typedef unsigned v4u  __attribute__((ext_vector_type(4)));

#if __has_builtin(__builtin_amdgcn_exp2f)
#define EXP2(x) __builtin_amdgcn_exp2f(x)
#else
#define EXP2(x) __builtin_exp2f(x)
#endif

// round-to-nearest-even f32 -> bf16
static __device__ __forceinline__ unsigned short f2b(float f) {
    unsigned int u = __float_as_uint(f);
    return (unsigned short)((u + 0x7FFFu + ((u >> 16) & 1u)) >> 16);
}
// single-instruction pack: dst = bf16(lo) | bf16(hi)<<16 (RNE)
static __device__ __forceinline__ unsigned cvtpk(float lo, float hi) {
    unsigned r;
    asm("v_cvt_pk_bf16_f32 %0, %1, %2" : "=v"(r) : "v"(lo), "v"(hi));
    return r;
}
// async global->LDS DMA, 16B/lane; LDS base wave-uniform, writes base+lane*16
static __device__ __forceinline__ void g2l16(const unsigned short* g, unsigned short* l) {
    __builtin_amdgcn_global_load_lds(
        (const __attribute__((address_space(1))) void*)g,
        (__attribute__((address_space(3))) void*)l, 16, 0, 0);
}

__global__ void cast_f32_bf16(const float* __restrict__ in,
                              unsigned short* __restrict__ out, int n4) {
    int i = blockIdx.x * blockDim.x + threadIdx.x;
    if (i < n4) {
        float4 v = reinterpret_cast<const float4*>(in)[i];
        ushort4 o;
        o.x = f2b(v.x); o.y = f2b(v.y); o.z = f2b(v.z); o.w = f2b(v.w);
        reinterpret_cast<ushort4*>(out)[i] = o;
    }
}

__global__ void cast4_f32_bf16(const float* __restrict__ i0, const float* __restrict__ i1,
                               const float* __restrict__ i2, const float* __restrict__ i3,
                               unsigned short* __restrict__ o0, unsigned short* __restrict__ o1,
                               unsigned short* __restrict__ o2, unsigned short* __restrict__ o3,
                               int n4) {
    int i = blockIdx.x * blockDim.x + threadIdx.x;
    if (i >= n4) return;
    const float* in; unsigned short* out;
    switch (blockIdx.y) {
        case 0: in = i0; out = o0; break;
        case 1: in = i1; out = o1; break;
        case 2: in = i2; out = o2; break;
        default: in = i3; out = o3; break;
    }
    float4 v = reinterpret_cast<const float4*>(in)[i];
    ushort4 o;
    o.x = f2b(v.x); o.y = f2b(v.y); o.z = f2b(v.z); o.w = f2b(v.w);
    reinterpret_cast<ushort4*>(out)[i] = o;
}

// Merged QKV: grid (MM/128, NH). One block computes Q,K,V for 128 rows x one
// head (64 features). K and V written FRAGMENT-NATIVE (MFMA A-frag layout):
// attn streams both as coalesced per-wave register frags from L2.
__global__ __launch_bounds__(256, 3) void gemm_qkv(
    const unsigned short* __restrict__ A,
    const unsigned short* __restrict__ Wq,
    const unsigned short* __restrict__ Wk,
    const unsigned short* __restrict__ Wv,
    const float* __restrict__ bq,
    const float* __restrict__ bk,
    const float* __restrict__ bvp,
    unsigned short* __restrict__ Qb,
    unsigned short* __restrict__ Kfo,
    unsigned short* __restrict__ Vf)
{
    __shared__ __align__(16) unsigned short As[128 * 64];      // 16 KB
    __shared__ __align__(16) unsigned short Bs[3][64 * 64];    // 24 KB

    const int tid  = threadIdx.x;
    const int w    = tid >> 6, lane = tid & 63;
    const int quad = lane >> 4, l16 = lane & 15;
    const int wm   = w & 1,  wn = w >> 1;
    const int lane8 = lane >> 3, sc = lane & 7;
    const int m0   = blockIdx.x * 128;
    const int h    = blockIdx.y;
    const int n0   = h * 64;

    v4f acc[3][4][2];
    #pragma unroll
    for (int s = 0; s < 3; ++s)
        #pragma unroll
        for (int i = 0; i < 4; ++i)
            #pragma unroll
            for (int j = 0; j < 2; ++j)
                acc[s][i][j] = v4f{0.f, 0.f, 0.f, 0.f};

    for (int kb = 0; kb < DIM; kb += 64) {
        __syncthreads();
        #pragma unroll
        for (int t = 0; t < 4; ++t) {
            int r8 = w * 32 + t * 8;
            int r  = r8 + lane8;
            int gch = sc ^ (r & 7);
            g2l16(&A[(size_t)(m0 + r) * DIM + kb + gch * 8], &As[r8 * 64]);
        }
        #pragma unroll
        for (int u = 0; u < 6; ++u) {
            int G = w * 6 + u;               // 0..23: set = G>>3, rowgrp = G&7
            int set = G >> 3, rg = G & 7;
            int row = rg * 8 + lane8;
            int gch = sc ^ (row & 7);
            const unsigned short* Wp = (set == 0) ? Wq : (set == 1) ? Wk : Wv;
            g2l16(&Wp[(size_t)(n0 + row) * DIM + kb + gch * 8], &Bs[set][rg * 8 * 64]);
        }
        __syncthreads();
        #pragma unroll
        for (int kk = 0; kk < 64; kk += 32) {
            int chb = kk >> 3;
            v8s a[4];
            #pragma unroll
            for (int i = 0; i < 4; ++i) {
                int m = wm * 64 + i * 16 + l16;
                a[i] = *reinterpret_cast<const v8s*>(
                    &As[m * 64 + (((chb + quad) ^ (m & 7)) << 3)]);
            }
            #pragma unroll
            for (int s = 0; s < 3; ++s) {
                v8s b[2];
                #pragma unroll
                for (int j = 0; j < 2; ++j) {
                    int n = wn * 32 + j * 16 + l16;
                    b[j] = *reinterpret_cast<const v8s*>(
                        &Bs[s][n * 64 + (((chb + quad) ^ (n & 7)) << 3)]);
                }
                #pragma unroll
                for (int i = 0; i < 4; ++i)
                    #pragma unroll
                    for (int j = 0; j < 2; ++j)
                        acc[s][i][j] = __builtin_amdgcn_mfma_f32_16x16x32_bf16(
                            a[i], b[j], acc[s][i][j], 0, 0, 0);
            }
        }
    }

    // ---- epilogues ----
    // Q: [bh][seq][hd], pre-scaled by 1/8 * log2(e)
    #pragma unroll
    for (int i = 0; i < 4; ++i) {
        #pragma unroll
        for (int j = 0; j < 2; ++j) {
            int hd = wn * 32 + j * 16 + l16;
            float bias_v = bq[n0 + hd];
            #pragma unroll
            for (int r = 0; r < 4; ++r) {
                int gm = m0 + wm * 64 + i * 16 + quad * 4 + r;
                int bb = gm >> 11, sq = gm & (SEQ - 1);
                Qb[((size_t)(bb * NH + h) * SEQ + sq) * HD + hd] =
                    f2b((acc[0][i][j][r] + bias_v) * 0.1803368801f);
            }
        }
    }
    // K: fragment-native Kf[bh][t][kh*4+c][lane(=hdbit3*32 + key&31)][8]
    #pragma unroll
    for (int i = 0; i < 4; ++i) {
        int kh = i >> 1;
        #pragma unroll
        for (int j = 0; j < 2; ++j) {
            int hd = wn * 32 + j * 16 + l16;
            int c  = hd >> 4;              // = wn*2 + j
            int half_a = (l16 >> 3) & 1;   // hd bit 3
            int jj = l16 & 7;              // hd low 3 bits
            float bias_v = bk[n0 + hd];
            int gm0 = m0 + wm * 64 + i * 16 + quad * 4;
            int bb = gm0 >> 11, sk = gm0 & (SEQ - 1);
            int t = sk >> 6;
            int l31k = (i & 1) * 16 + quad * 4;          // + r below
            size_t frag = ((size_t)(bb * NH + h) * NKB + t) * 8 + kh * 4 + c;
            unsigned short* dst = &Kfo[frag * 512 + (half_a * 32 + l31k) * 8 + jj];
            #pragma unroll
            for (int r = 0; r < 4; ++r)
                dst[r * 8] = f2b(acc[1][i][j][r] + bias_v);
        }
    }
    // V: fragment-native Vf[bh][kbi][hb*4+c][lane][8]
    #pragma unroll
    for (int i = 0; i < 4; ++i) {
        #pragma unroll
        for (int j = 0; j < 2; ++j) {
            int hd = wn * 32 + j * 16 + l16;
            int hb = hd >> 5, l31v = hd & 31;
            float bias_v = bvp[n0 + hd];
            int gm0 = m0 + wm * 64 + i * 16 + quad * 4;
            int bb = gm0 >> 11, sk = gm0 & (SEQ - 1);
            int kbi = sk >> 6;
            int halfv = quad >> 1, j0 = (quad & 1) * 4;
            ushort4 pkv;
            pkv.x = f2b(acc[2][i][j][0] + bias_v);
            pkv.y = f2b(acc[2][i][j][1] + bias_v);
            pkv.z = f2b(acc[2][i][j][2] + bias_v);
            pkv.w = f2b(acc[2][i][j][3] + bias_v);
            size_t frag = ((size_t)(bb * NH + h) * NKB + kbi) * 8 + hb * 4 + i;
            *reinterpret_cast<ushort4*>(
                &Vf[frag * 512 + (halfv * 32 + l31v) * 8 + j0]) = pkv;
        }
    }
}

// Output projection: 128x64 tiles, grid (64, 12) = 768 blocks = 3 WG/CU even.
__global__ __launch_bounds__(256, 3) void gemm_o(
    const unsigned short* __restrict__ A,
    const unsigned short* __restrict__ W,
    const float* __restrict__ bias,
    float* __restrict__ out)
{
    __shared__ __align__(16) unsigned short As[128 * 64];   // 16 KB
    __shared__ __align__(16) unsigned short Bs[64 * 64];    // 8 KB

    const int tid  = threadIdx.x;
    const int w    = tid >> 6, lane = tid & 63;
    const int quad = lane >> 4, l16 = lane & 15;
    const int wm   = w & 1,  wn = w >> 1;
    const int lane8 = lane >> 3, sc = lane & 7;
    const int m0  = blockIdx.x * 128;
    const int n0l = blockIdx.y * 64;

    v4f acc[4][2];
    #pragma unroll
    for (int i = 0; i < 4; ++i)
        #pragma unroll
        for (int j = 0; j < 2; ++j)
            acc[i][j] = v4f{0.f, 0.f, 0.f, 0.f};

    for (int kb = 0; kb < DIM; kb += 64) {
        __syncthreads();
        #pragma unroll
        for (int t = 0; t < 4; ++t) {
            int r8 = w * 32 + t * 8;
            int r  = r8 + lane8;
            int gch = sc ^ (r & 7);
            g2l16(&A[(size_t)(m0 + r) * DIM + kb + gch * 8], &As[r8 * 64]);
        }
        #pragma unroll
        for (int t = 0; t < 2; ++t) {
            int r8 = (w * 2 + t) * 8;
            int r  = r8 + lane8;
            int gch = sc ^ (r & 7);
            g2l16(&W[(size_t)(n0l + r) * DIM + kb + gch * 8], &Bs[r8 * 64]);
        }
        __syncthreads();
        #pragma unroll
        for (int kk = 0; kk < 64; kk += 32) {
            v8s a[4], b[2];
            int chb = kk >> 3;
            #pragma unroll
            for (int i = 0; i < 4; ++i) {
                int m = wm * 64 + i * 16 + l16;
                a[i] = *reinterpret_cast<const v8s*>(
                    &As[m * 64 + (((chb + quad) ^ (m & 7)) << 3)]);
            }
            #pragma unroll
            for (int j = 0; j < 2; ++j) {
                int n = wn * 32 + j * 16 + l16;
                b[j] = *reinterpret_cast<const v8s*>(
                    &Bs[n * 64 + (((chb + quad) ^ (n & 7)) << 3)]);
            }
            #pragma unroll
            for (int i = 0; i < 4; ++i)
                #pragma unroll
                for (int j = 0; j < 2; ++j)
                    acc[i][j] = __builtin_amdgcn_mfma_f32_16x16x32_bf16(a[i], b[j], acc[i][j], 0, 0, 0);
        }
    }

    #pragma unroll
    for (int i = 0; i < 4; ++i) {
        #pragma unroll
        for (int j = 0; j < 2; ++j) {
            int gn = n0l + wn * 32 + j * 16 + l16;
            float bias_v = bias[gn];
            #pragma unroll
            for (int r = 0; r < 4; ++r) {
                int gm = m0 + wm * 64 + i * 16 + quad * 4 + r;
                out[(size_t)gm * DIM + gn] = acc[i][j][r] + bias_v;
            }
        }
    }
}

// ---------------------------------------------------------------------------
// Transposed flash attention, R8: R5's verified zero-LDS/zero-barrier body
// (passed, absmax 4.88e-4, 79us) with two serial-chain cuts:
//  (1) partner exchange via v_permlane32_swap_b32 (gfx950): vdst'={a.lo,b.lo},
//      vsrc'={a.hi,b.hi} -- exactly the lane<->lane^32 exchange. Replaces
//      8 ds_bpermute (~40cy DS latency each) + 24 cndmask selects per tile
//      with 8 VALU ops; the main loop becomes 100% DS-free.
//  (2) PV accumulator chain split: o0/o1 were 4-deep dependent MFMA chains
//      per tile; a/b accumulator pairs (cp 0,1 -> a; cp 2,3 -> b) halve the
//      depth; single epilogue add. +32 VGPR (-> ~105, under the 168 cap).
// No scheduling hints (R3 lesson). Dual-stream (R7) abandoned: its ~250-VGPR
// live set would spill at the 168-VGPR cap of 3 waves/SIMD.
// ---------------------------------------------------------------------------
__global__ __launch_bounds__(256, 3) void attn(
    const unsigned short* __restrict__ Q,
    const unsigned short* __restrict__ Kf,
    const unsigned short* __restrict__ Vf,
    unsigned short* __restrict__ ctx)
{
    const int tid  = threadIdx.x;
    const int w    = tid >> 6, lane = tid & 63;
    const int l31  = lane & 31, half = lane >> 5;

    // XCD swizzle: 768 blocks, 8 XCDs -> XCD k owns bh [6k, 6k+6) x 16 q-tiles
    const int lblk = blockIdx.y * 16 + blockIdx.x;       // gridDim.x == 16
    const int vblk = (lblk & 7) * 96 + (lblk >> 3);
    const int bh   = vblk >> 4;
    const int b    = bh / NH, h = bh % NH;
    const int q0   = (vblk & 15) * 128 + w * 32;

    const unsigned short* Qp = Q  + ((size_t)bh * SEQ + q0) * HD;
    const unsigned short* Kh = Kf + (size_t)bh * (NKB * 8 * 512) + lane * 8;
    const unsigned short* Vh = Vf + (size_t)bh * (NKB * 8 * 512) + lane * 8;

    // Q B-frag: B[n=q=l31][k = c*16 + half*8 + j] (pre-scaled by 0.125*log2e)
    v8s bq[4];
    #pragma unroll
    for (int c = 0; c < 4; ++c)
        bq[c] = *reinterpret_cast<const v8s*>(&Qp[l31 * HD + c * 16 + half * 8]);

    // K/V A-frags for tile 0 (coalesced: consecutive lanes -> consecutive 16B)
    v8s ka[2][4], va[2][4];
    #pragma unroll
    for (int g = 0; g < 8; ++g)
        reinterpret_cast<v8s*>(ka)[g] = *reinterpret_cast<const v8s*>(&Kh[(size_t)g * 512]);
    #pragma unroll
    for (int g = 0; g < 8; ++g)
        reinterpret_cast<v8s*>(va)[g] = *reinterpret_cast<const v8s*>(&Vh[(size_t)g * 512]);

    v16f o0a, o0b, o1a, o1b, Z;
    #pragma unroll
    for (int i = 0; i < 16; ++i) {
        o0a[i] = 0.f; o0b[i] = 0.f; o1a[i] = 0.f; o1b[i] = 0.f; Z[i] = 0.f;
    }
    float li = 0.f;

    for (int it = 0; it < NKB; ++it) {
        // S^T[key][q]: two independent 4-deep MFMA chains (keys 0..31 / 32..63)
        v16f s0 = __builtin_amdgcn_mfma_f32_32x32x16_bf16(ka[0][0], bq[0], Z, 0, 0, 0);
        v16f s1 = __builtin_amdgcn_mfma_f32_32x32x16_bf16(ka[1][0], bq[0], Z, 0, 0, 0);
        #pragma unroll
        for (int c = 1; c < 4; ++c) {
            s0 = __builtin_amdgcn_mfma_f32_32x32x16_bf16(ka[0][c], bq[c], s0, 0, 0, 0);
            s1 = __builtin_amdgcn_mfma_f32_32x32x16_bf16(ka[1][c], bq[c], s1, 0, 0, 0);
        }

        // prefetch next K tile into ka; its ~L2 latency hides under
        // exp/pack/swap + PV (~600 cy)
        {
            int nt = (it + 1 < NKB) ? it + 1 : it;
            #pragma unroll
            for (int g = 0; g < 8; ++g)
                reinterpret_cast<v8s*>(ka)[g] =
                    *reinterpret_cast<const v8s*>(&Kh[((size_t)nt * 8 + g) * 512]);
        }

        // exp2 + lane-local li + pack key-pairs (1 instr per pair via cvt_pk)
        unsigned pk[8][2];
        #pragma unroll
        for (int g = 0; g < 4; ++g) {
            float e0 = EXP2(s0[4*g+0]), e1 = EXP2(s0[4*g+1]);
            float e2 = EXP2(s0[4*g+2]), e3 = EXP2(s0[4*g+3]);
            li += (e0 + e1) + (e2 + e3);
            pk[g][0] = cvtpk(e0, e1);
            pk[g][1] = cvtpk(e2, e3);
            float f0 = EXP2(s1[4*g+0]), f1 = EXP2(s1[4*g+1]);
            float f2 = EXP2(s1[4*g+2]), f3 = EXP2(s1[4*g+3]);
            li += (f0 + f1) + (f2 + f3);
            pk[4+g][0] = cvtpk(f0, f1);
            pk[4+g][1] = cvtpk(f2, f3);
        }

        // P^T B-frags: partner (lane^32) holds the complementary 4-key blocks.
        // v_permlane32_swap_b32 a, b: a' = {a.lo, b.lo}, b' = {a.hi, b.hi}.
        //   lanes<32 : fw = {own a0, own a1, partner a0, partner a1} = {a0',a1',b0',b1'}
        //   lanes>=32: fw = {partner b0, partner b1, own b0, own b1} = {a0',a1',b0',b1'}
        // identical to the verified shfl_xor+select construction.
        #pragma unroll
        for (int cp = 0; cp < 4; ++cp) {
            unsigned a0 = pk[2*cp][0],   a1 = pk[2*cp][1];
            unsigned b0 = pk[2*cp+1][0], b1 = pk[2*cp+1][1];
            asm("v_permlane32_swap_b32 %0, %1" : "+v"(a0), "+v"(b0));
            asm("v_permlane32_swap_b32 %0, %1" : "+v"(a1), "+v"(b1));
            v4u fw;
            fw.x = a0; fw.y = a1; fw.z = b0; fw.w = b1;
            v8s pf = __builtin_bit_cast(v8s, fw);
            if (cp < 2) {
                o0a = __builtin_amdgcn_mfma_f32_32x32x16_bf16(va[0][cp], pf, o0a, 0, 0, 0);
                o1a = __builtin_amdgcn_mfma_f32_32x32x16_bf16(va[1][cp], pf, o1a, 0, 0, 0);
            } else {
                o0b = __builtin_amdgcn_mfma_f32_32x32x16_bf16(va[0][cp], pf, o0b, 0, 0, 0);
                o1b = __builtin_amdgcn_mfma_f32_32x32x16_bf16(va[1][cp], pf, o1b, 0, 0, 0);
            }
        }

        // prefetch next V tile (lands during next tile's QK^T + softmax)
        {
            int nt = (it + 1 < NKB) ? it + 1 : it;
            #pragma unroll
            for (int g = 0; g < 8; ++g)
                reinterpret_cast<v8s*>(va)[g] =
                    *reinterpret_cast<const v8s*>(&Vh[((size_t)nt * 8 + g) * 512]);
        }
    }

    // li total = own 32 keys + partner's 32 keys (same q)
    float inv = 1.0f / (li + __shfl_xor(li, 32));

    // O^T: lane holds q = q0+l31; rows hd = (reg&3)+8*(reg>>2)+4*half (+32 for o1)
    const int q = q0 + l31;
    size_t base = ((size_t)(b * SEQ + q)) * DIM + h * HD;
    #pragma unroll
    for (int g = 0; g < 4; ++g) {
        int hd0 = 8 * g + 4 * half;
        uint2 u0, u1;
        u0.x = cvtpk((o0a[4*g+0] + o0b[4*g+0]) * inv, (o0a[4*g+1] + o0b[4*g+1]) * inv);
        u0.y = cvtpk((o0a[4*g+2] + o0b[4*g+2]) * inv, (o0a[4*g+3] + o0b[4*g+3]) * inv);
        u1.x = cvtpk((o1a[4*g+0] + o1b[4*g+0]) * inv, (o1a[4*g+1] + o1b[4*g+1]) * inv);
        u1.y = cvtpk((o1a[4*g+2] + o1b[4*g+2]) * inv, (o1a[4*g+3] + o1b[4*g+3]) * inv);
        *reinterpret_cast<uint2*>(&ctx[base + hd0])      = u0;
        *reinterpret_cast<uint2*>(&ctx[base + 32 + hd0]) = u1;
    }
}

extern "C" void kernel_launch(void* const* d_in, const int* in_sizes, int n_in,
                              void* d_out, int out_size, void* d_ws, size_t ws_size,
                              hipStream_t stream) {
    const float* x  = (const float*)d_in[0];
    const float* qw = (const float*)d_in[1]; const float* qb = (const float*)d_in[2];
    const float* kw = (const float*)d_in[3]; const float* kb = (const float*)d_in[4];
    const float* vw = (const float*)d_in[5]; const float* vb = (const float*)d_in[6];
    const float* ow = (const float*)d_in[7]; const float* ob = (const float*)d_in[8];
    float* out = (float*)d_out;

    char* ws = (char*)d_ws;
    size_t off = 0;
    auto alloc = [&](size_t bytes) -> unsigned short* {
        unsigned short* p = (unsigned short*)(ws + off);
        off += (bytes + 255) & ~(size_t)255;
        return p;
    };
    const size_t XB = (size_t)MM * DIM * 2;
    const size_t WB = (size_t)DIM * DIM * 2;
    const size_t QB = (size_t)NB * NH * SEQ * HD * 2;

    unsigned short* xb  = alloc(XB);
    unsigned short* wqb = alloc(WB);
    unsigned short* wkb = alloc(WB);
    unsigned short* wvb = alloc(WB);
    unsigned short* wob = alloc(WB);
    unsigned short* Qb  = alloc(QB);
    unsigned short* Kfb = alloc(QB);   // fragment-native K
    unsigned short* Vfb = alloc(QB);   // fragment-native V
    unsigned short* ctx = alloc(XB);

    const int n4x = MM * DIM / 4;
    const int n4w = DIM * DIM / 4;
    cast_f32_bf16<<<(n4x + 255) / 256, 256, 0, stream>>>(x, xb, n4x);
    cast4_f32_bf16<<<dim3((n4w + 255) / 256, 4), 256, 0, stream>>>(
        qw, kw, vw, ow, wqb, wkb, wvb, wob, n4w);

    gemm_qkv<<<dim3(MM / 128, NH), 256, 0, stream>>>(
        xb, wqb, wkb, wvb, qb, kb, vb, Qb, Kfb, Vfb);

    attn<<<dim3(SEQ / 128, NB * NH), 256, 0, stream>>>(Qb, Kfb, Vfb, ctx);

    gemm_o<<<dim3(MM / 128, DIM / 64), 256, 0, stream>>>(ctx, wob, ob, out);
}

// Round 9
// 205.298 us; speedup vs baseline: 1.1765x; 1.0108x over previous
//
#include <hip/hip_runtime.h>
#include <hip/hip_bf16.h>

#define NH  12
#define HD  64
#define DIM 768
#define SEQ 2048
#define NB  4
#define MM  (NB*SEQ)   // 8192 rows
#define NKB (SEQ/64)   // 32 key-blocks per head

typedef short    v8s  __attribute__((ext_vector_type(8)));   // 8 x bf16 (4 VGPRs)
typedef float    v4f  __attribute__((ext_vector_type(4)));
typedef float    v16f __attribute__((ext_vector_type(16)));
typedef unsigned v4u  __attribute__((ext_vector_type(4)));

#if __has_builtin(__builtin_amdgcn_exp2f)
#define EXP2(x) __builtin_amdgcn_exp2f(x)
#else
#define EXP2(x) __builtin_exp2f(x)
#endif

// round-to-nearest-even f32 -> bf16
static __device__ __forceinline__ unsigned short f2b(float f) {
    unsigned int u = __float_as_uint(f);
    return (unsigned short)((u + 0x7FFFu + ((u >> 16) & 1u)) >> 16);
}
// single-instruction pack: dst = bf16(lo) | bf16(hi)<<16 (RNE)
static __device__ __forceinline__ unsigned cvtpk(float lo, float hi) {
    unsigned r;
    asm("v_cvt_pk_bf16_f32 %0, %1, %2" : "=v"(r) : "v"(lo), "v"(hi));
    return r;
}
// async global->LDS DMA, 16B/lane; LDS base wave-uniform, writes base+lane*16
static __device__ __forceinline__ void g2l16(const unsigned short* g, unsigned short* l) {
    __builtin_amdgcn_global_load_lds(
        (const __attribute__((address_space(1))) void*)g,
        (__attribute__((address_space(3))) void*)l, 16, 0, 0);
}

__global__ void cast_f32_bf16(const float* __restrict__ in,
                              unsigned short* __restrict__ out, int n4) {
    int i = blockIdx.x * blockDim.x + threadIdx.x;
    if (i < n4) {
        float4 v = reinterpret_cast<const float4*>(in)[i];
        ushort4 o;
        o.x = f2b(v.x); o.y = f2b(v.y); o.z = f2b(v.z); o.w = f2b(v.w);
        reinterpret_cast<ushort4*>(out)[i] = o;
    }
}

__global__ void cast4_f32_bf16(const float* __restrict__ i0, const float* __restrict__ i1,
                               const float* __restrict__ i2, const float* __restrict__ i3,
                               unsigned short* __restrict__ o0, unsigned short* __restrict__ o1,
                               unsigned short* __restrict__ o2, unsigned short* __restrict__ o3,
                               int n4) {
    int i = blockIdx.x * blockDim.x + threadIdx.x;
    if (i >= n4) return;
    const float* in; unsigned short* out;
    switch (blockIdx.y) {
        case 0: in = i0; out = o0; break;
        case 1: in = i1; out = o1; break;
        case 2: in = i2; out = o2; break;
        default: in = i3; out = o3; break;
    }
    float4 v = reinterpret_cast<const float4*>(in)[i];
    ushort4 o;
    o.x = f2b(v.x); o.y = f2b(v.y); o.z = f2b(v.z); o.w = f2b(v.w);
    reinterpret_cast<ushort4*>(out)[i] = o;
}

// Merged QKV: grid (MM/128, NH). One block computes Q,K,V for 128 rows x one
// head (64 features). K and V written FRAGMENT-NATIVE (MFMA A-frag layout):
// attn DMA-stages both linearly into LDS and reads conflict-free.
__global__ __launch_bounds__(256, 3) void gemm_qkv(
    const unsigned short* __restrict__ A,
    const unsigned short* __restrict__ Wq,
    const unsigned short* __restrict__ Wk,
    const unsigned short* __restrict__ Wv,
    const float* __restrict__ bq,
    const float* __restrict__ bk,
    const float* __restrict__ bvp,
    unsigned short* __restrict__ Qb,
    unsigned short* __restrict__ Kfo,
    unsigned short* __restrict__ Vf)
{
    __shared__ __align__(16) unsigned short As[128 * 64];      // 16 KB
    __shared__ __align__(16) unsigned short Bs[3][64 * 64];    // 24 KB

    const int tid  = threadIdx.x;
    const int w    = tid >> 6, lane = tid & 63;
    const int quad = lane >> 4, l16 = lane & 15;
    const int wm   = w & 1,  wn = w >> 1;
    const int lane8 = lane >> 3, sc = lane & 7;
    const int m0   = blockIdx.x * 128;
    const int h    = blockIdx.y;
    const int n0   = h * 64;

    v4f acc[3][4][2];
    #pragma unroll
    for (int s = 0; s < 3; ++s)
        #pragma unroll
        for (int i = 0; i < 4; ++i)
            #pragma unroll
            for (int j = 0; j < 2; ++j)
                acc[s][i][j] = v4f{0.f, 0.f, 0.f, 0.f};

    for (int kb = 0; kb < DIM; kb += 64) {
        __syncthreads();
        #pragma unroll
        for (int t = 0; t < 4; ++t) {
            int r8 = w * 32 + t * 8;
            int r  = r8 + lane8;
            int gch = sc ^ (r & 7);
            g2l16(&A[(size_t)(m0 + r) * DIM + kb + gch * 8], &As[r8 * 64]);
        }
        #pragma unroll
        for (int u = 0; u < 6; ++u) {
            int G = w * 6 + u;               // 0..23: set = G>>3, rowgrp = G&7
            int set = G >> 3, rg = G & 7;
            int row = rg * 8 + lane8;
            int gch = sc ^ (row & 7);
            const unsigned short* Wp = (set == 0) ? Wq : (set == 1) ? Wk : Wv;
            g2l16(&Wp[(size_t)(n0 + row) * DIM + kb + gch * 8], &Bs[set][rg * 8 * 64]);
        }
        __syncthreads();
        #pragma unroll
        for (int kk = 0; kk < 64; kk += 32) {
            int chb = kk >> 3;
            v8s a[4];
            #pragma unroll
            for (int i = 0; i < 4; ++i) {
                int m = wm * 64 + i * 16 + l16;
                a[i] = *reinterpret_cast<const v8s*>(
                    &As[m * 64 + (((chb + quad) ^ (m & 7)) << 3)]);
            }
            #pragma unroll
            for (int s = 0; s < 3; ++s) {
                v8s b[2];
                #pragma unroll
                for (int j = 0; j < 2; ++j) {
                    int n = wn * 32 + j * 16 + l16;
                    b[j] = *reinterpret_cast<const v8s*>(
                        &Bs[s][n * 64 + (((chb + quad) ^ (n & 7)) << 3)]);
                }
                #pragma unroll
                for (int i = 0; i < 4; ++i)
                    #pragma unroll
                    for (int j = 0; j < 2; ++j)
                        acc[s][i][j] = __builtin_amdgcn_mfma_f32_16x16x32_bf16(
                            a[i], b[j], acc[s][i][j], 0, 0, 0);
            }
        }
    }

    // ---- epilogues ----
    // Q: [bh][seq][hd], pre-scaled by 1/8 * log2(e)
    #pragma unroll
    for (int i = 0; i < 4; ++i) {
        #pragma unroll
        for (int j = 0; j < 2; ++j) {
            int hd = wn * 32 + j * 16 + l16;
            float bias_v = bq[n0 + hd];
            #pragma unroll
            for (int r = 0; r < 4; ++r) {
                int gm = m0 + wm * 64 + i * 16 + quad * 4 + r;
                int bb = gm >> 11, sq = gm & (SEQ - 1);
                Qb[((size_t)(bb * NH + h) * SEQ + sq) * HD + hd] =
                    f2b((acc[0][i][j][r] + bias_v) * 0.1803368801f);
            }
        }
    }
    // K: fragment-native Kf[bh][t][kh*4+c][lane(=hdbit3*32 + key&31)][8]
    #pragma unroll
    for (int i = 0; i < 4; ++i) {
        int kh = i >> 1;
        #pragma unroll
        for (int j = 0; j < 2; ++j) {
            int hd = wn * 32 + j * 16 + l16;
            int c  = hd >> 4;              // = wn*2 + j
            int half_a = (l16 >> 3) & 1;   // hd bit 3
            int jj = l16 & 7;              // hd low 3 bits
            float bias_v = bk[n0 + hd];
            int gm0 = m0 + wm * 64 + i * 16 + quad * 4;
            int bb = gm0 >> 11, sk = gm0 & (SEQ - 1);
            int t = sk >> 6;
            int l31k = (i & 1) * 16 + quad * 4;          // + r below
            size_t frag = ((size_t)(bb * NH + h) * NKB + t) * 8 + kh * 4 + c;
            unsigned short* dst = &Kfo[frag * 512 + (half_a * 32 + l31k) * 8 + jj];
            #pragma unroll
            for (int r = 0; r < 4; ++r)
                dst[r * 8] = f2b(acc[1][i][j][r] + bias_v);
        }
    }
    // V: fragment-native Vf[bh][kbi][hb*4+c][lane][8]
    #pragma unroll
    for (int i = 0; i < 4; ++i) {
        #pragma unroll
        for (int j = 0; j < 2; ++j) {
            int hd = wn * 32 + j * 16 + l16;
            int hb = hd >> 5, l31v = hd & 31;
            float bias_v = bvp[n0 + hd];
            int gm0 = m0 + wm * 64 + i * 16 + quad * 4;
            int bb = gm0 >> 11, sk = gm0 & (SEQ - 1);
            int kbi = sk >> 6;
            int halfv = quad >> 1, j0 = (quad & 1) * 4;
            ushort4 pkv;
            pkv.x = f2b(acc[2][i][j][0] + bias_v);
            pkv.y = f2b(acc[2][i][j][1] + bias_v);
            pkv.z = f2b(acc[2][i][j][2] + bias_v);
            pkv.w = f2b(acc[2][i][j][3] + bias_v);
            size_t frag = ((size_t)(bb * NH + h) * NKB + kbi) * 8 + hb * 4 + i;
            *reinterpret_cast<ushort4*>(
                &Vf[frag * 512 + (halfv * 32 + l31v) * 8 + j0]) = pkv;
        }
    }
}

// Output projection: 128x64 tiles, grid (64, 12) = 768 blocks = 3 WG/CU even.
__global__ __launch_bounds__(256, 3) void gemm_o(
    const unsigned short* __restrict__ A,
    const unsigned short* __restrict__ W,
    const float* __restrict__ bias,
    float* __restrict__ out)
{
    __shared__ __align__(16) unsigned short As[128 * 64];   // 16 KB
    __shared__ __align__(16) unsigned short Bs[64 * 64];    // 8 KB

    const int tid  = threadIdx.x;
    const int w    = tid >> 6, lane = tid & 63;
    const int quad = lane >> 4, l16 = lane & 15;
    const int wm   = w & 1,  wn = w >> 1;
    const int lane8 = lane >> 3, sc = lane & 7;
    const int m0  = blockIdx.x * 128;
    const int n0l = blockIdx.y * 64;

    v4f acc[4][2];
    #pragma unroll
    for (int i = 0; i < 4; ++i)
        #pragma unroll
        for (int j = 0; j < 2; ++j)
            acc[i][j] = v4f{0.f, 0.f, 0.f, 0.f};

    for (int kb = 0; kb < DIM; kb += 64) {
        __syncthreads();
        #pragma unroll
        for (int t = 0; t < 4; ++t) {
            int r8 = w * 32 + t * 8;
            int r  = r8 + lane8;
            int gch = sc ^ (r & 7);
            g2l16(&A[(size_t)(m0 + r) * DIM + kb + gch * 8], &As[r8 * 64]);
        }
        #pragma unroll
        for (int t = 0; t < 2; ++t) {
            int r8 = (w * 2 + t) * 8;
            int r  = r8 + lane8;
            int gch = sc ^ (r & 7);
            g2l16(&W[(size_t)(n0l + r) * DIM + kb + gch * 8], &Bs[r8 * 64]);
        }
        __syncthreads();
        #pragma unroll
        for (int kk = 0; kk < 64; kk += 32) {
            v8s a[4], b[2];
            int chb = kk >> 3;
            #pragma unroll
            for (int i = 0; i < 4; ++i) {
                int m = wm * 64 + i * 16 + l16;
                a[i] = *reinterpret_cast<const v8s*>(
                    &As[m * 64 + (((chb + quad) ^ (m & 7)) << 3)]);
            }
            #pragma unroll
            for (int j = 0; j < 2; ++j) {
                int n = wn * 32 + j * 16 + l16;
                b[j] = *reinterpret_cast<const v8s*>(
                    &Bs[n * 64 + (((chb + quad) ^ (n & 7)) << 3)]);
            }
            #pragma unroll
            for (int i = 0; i < 4; ++i)
                #pragma unroll
                for (int j = 0; j < 2; ++j)
                    acc[i][j] = __builtin_amdgcn_mfma_f32_16x16x32_bf16(a[i], b[j], acc[i][j], 0, 0, 0);
        }
    }

    #pragma unroll
    for (int i = 0; i < 4; ++i) {
        #pragma unroll
        for (int j = 0; j < 2; ++j) {
            int gn = n0l + wn * 32 + j * 16 + l16;
            float bias_v = bias[gn];
            #pragma unroll
            for (int r = 0; r < 4; ++r) {
                int gm = m0 + wm * 64 + i * 16 + quad * 4 + r;
                out[(size_t)gm * DIM + gn] = acc[i][j][r] + bias_v;
            }
        }
    }
}

// ---------------------------------------------------------------------------
// Transposed flash attention, R9: LDS double-buffer for BOTH K and V.
// R8 diagnosis: all 4 waves of a block stream IDENTICAL K/V per-wave from L2
// -> 4x redundant reads = 22 TB/s aggregate (~64% of L2 ceiling) -> queuing
// inflates load latency past the ~450cy prefetch distance -> per-tile vmcnt
// stalls (1784 cy wall vs ~650 issued). Fix: stage K+V once per block via
// global_load_lds into 2x16KB double buffers (R2-verified mechanism: linear
// fragment-native layout, 0 bank conflicts), minimum-2-phase pipeline:
//   prologue STAGE(0,buf0); per tile: __syncthreads() [drains my tile-it
//   DMAs, issued a full compute-phase (~600cy) ago -> ~free] -> STAGE(it+1,
//   other buf) -> compute from LDS.
// One plain __syncthreads per tile; no counted vmcnt, no inline-asm sync
// (R3/R6 lesson). L2 traffic drops 4x to ~5.6 TB/s -> L2 latency ~250cy,
// fully covered. Keeps R8-verified permlane32_swap exchange, split PV
// accumulators, cvtpk, XCD swizzle. LDS 32KB x 3 blocks = 96KB/CU.
// ---------------------------------------------------------------------------
__global__ __launch_bounds__(256, 3) void attn(
    const unsigned short* __restrict__ Q,
    const unsigned short* __restrict__ Kf,
    const unsigned short* __restrict__ Vf,
    unsigned short* __restrict__ ctx)
{
    __shared__ __align__(16) unsigned short Ks[2][8 * 512];   // 16 KB
    __shared__ __align__(16) unsigned short Vs[2][8 * 512];   // 16 KB

    const int tid  = threadIdx.x;
    const int w    = tid >> 6, lane = tid & 63;
    const int l31  = lane & 31, half = lane >> 5;

    // XCD swizzle: 768 blocks, 8 XCDs -> XCD k owns bh [6k, 6k+6) x 16 q-tiles
    const int lblk = blockIdx.y * 16 + blockIdx.x;       // gridDim.x == 16
    const int vblk = (lblk & 7) * 96 + (lblk >> 3);
    const int bh   = vblk >> 4;
    const int b    = bh / NH, h = bh % NH;
    const int q0   = (vblk & 15) * 128 + w * 32;

    const unsigned short* Qp = Q  + ((size_t)bh * SEQ + q0) * HD;
    const unsigned short* Kh = Kf + (size_t)bh * (NKB * 8 * 512);
    const unsigned short* Vh = Vf + (size_t)bh * (NKB * 8 * 512);

    // Q B-frag: B[n=q=l31][k = c*16 + half*8 + j] (pre-scaled by 0.125*log2e)
    v8s bq[4];
    #pragma unroll
    for (int c = 0; c < 4; ++c)
        bq[c] = *reinterpret_cast<const v8s*>(&Qp[l31 * HD + c * 16 + half * 8]);

    // wave w stages K frags {2w, 2w+1} and V frags {2w, 2w+1} of each tile
    #define STAGE(it_, buf_)                                                   \
        do {                                                                   \
            _Pragma("unroll")                                                  \
            for (int t = 0; t < 2; ++t) {                                      \
                int g = w * 2 + t;                                             \
                g2l16(&Kh[((size_t)(it_) * 8 + g) * 512 + lane * 8],           \
                      &Ks[buf_][g * 512]);                                     \
                g2l16(&Vh[((size_t)(it_) * 8 + g) * 512 + lane * 8],           \
                      &Vs[buf_][g * 512]);                                     \
            }                                                                  \
        } while (0)

    STAGE(0, 0);

    v16f o0a, o0b, o1a, o1b, Z;
    #pragma unroll
    for (int i = 0; i < 16; ++i) {
        o0a[i] = 0.f; o0b[i] = 0.f; o1a[i] = 0.f; o1b[i] = 0.f; Z[i] = 0.f;
    }
    float li = 0.f;

    int cur = 0;
    for (int it = 0; it < NKB; ++it) {
        __syncthreads();                       // certifies STAGE(it) block-wide
        if (it + 1 < NKB) STAGE(it + 1, cur ^ 1);

        const unsigned short* Kb_ = Ks[cur];
        const unsigned short* Vb_ = Vs[cur];

        // S^T[key][q]: two independent 4-deep MFMA chains (keys 0..31 / 32..63)
        v16f s0, s1;
        {
            v8s k0 = *reinterpret_cast<const v8s*>(&Kb_[lane * 8]);
            v8s k1 = *reinterpret_cast<const v8s*>(&Kb_[4 * 512 + lane * 8]);
            s0 = __builtin_amdgcn_mfma_f32_32x32x16_bf16(k0, bq[0], Z, 0, 0, 0);
            s1 = __builtin_amdgcn_mfma_f32_32x32x16_bf16(k1, bq[0], Z, 0, 0, 0);
            #pragma unroll
            for (int c = 1; c < 4; ++c) {
                v8s kc0 = *reinterpret_cast<const v8s*>(&Kb_[(size_t)c * 512 + lane * 8]);
                v8s kc1 = *reinterpret_cast<const v8s*>(&Kb_[(size_t)(4 + c) * 512 + lane * 8]);
                s0 = __builtin_amdgcn_mfma_f32_32x32x16_bf16(kc0, bq[c], s0, 0, 0, 0);
                s1 = __builtin_amdgcn_mfma_f32_32x32x16_bf16(kc1, bq[c], s1, 0, 0, 0);
            }
        }

        // exp2 + lane-local li + pack key-pairs (1 instr per pair via cvt_pk)
        unsigned pk[8][2];
        #pragma unroll
        for (int g = 0; g < 4; ++g) {
            float e0 = EXP2(s0[4*g+0]), e1 = EXP2(s0[4*g+1]);
            float e2 = EXP2(s0[4*g+2]), e3 = EXP2(s0[4*g+3]);
            li += (e0 + e1) + (e2 + e3);
            pk[g][0] = cvtpk(e0, e1);
            pk[g][1] = cvtpk(e2, e3);
            float f0 = EXP2(s1[4*g+0]), f1 = EXP2(s1[4*g+1]);
            float f2 = EXP2(s1[4*g+2]), f3 = EXP2(s1[4*g+3]);
            li += (f0 + f1) + (f2 + f3);
            pk[4+g][0] = cvtpk(f0, f1);
            pk[4+g][1] = cvtpk(f2, f3);
        }

        // P^T B-frags via v_permlane32_swap_b32 (R8-verified); V from LDS.
        #pragma unroll
        for (int cp = 0; cp < 4; ++cp) {
            unsigned a0 = pk[2*cp][0],   a1 = pk[2*cp][1];
            unsigned b0 = pk[2*cp+1][0], b1 = pk[2*cp+1][1];
            asm("v_permlane32_swap_b32 %0, %1" : "+v"(a0), "+v"(b0));
            asm("v_permlane32_swap_b32 %0, %1" : "+v"(a1), "+v"(b1));
            v4u fw;
            fw.x = a0; fw.y = a1; fw.z = b0; fw.w = b1;
            v8s pf = __builtin_bit_cast(v8s, fw);
            v8s v0 = *reinterpret_cast<const v8s*>(&Vb_[(size_t)cp * 512 + lane * 8]);
            v8s v1 = *reinterpret_cast<const v8s*>(&Vb_[(size_t)(4 + cp) * 512 + lane * 8]);
            if (cp < 2) {
                o0a = __builtin_amdgcn_mfma_f32_32x32x16_bf16(v0, pf, o0a, 0, 0, 0);
                o1a = __builtin_amdgcn_mfma_f32_32x32x16_bf16(v1, pf, o1a, 0, 0, 0);
            } else {
                o0b = __builtin_amdgcn_mfma_f32_32x32x16_bf16(v0, pf, o0b, 0, 0, 0);
                o1b = __builtin_amdgcn_mfma_f32_32x32x16_bf16(v1, pf, o1b, 0, 0, 0);
            }
        }

        cur ^= 1;
    }
    #undef STAGE

    // li total = own 32 keys + partner's 32 keys (same q)
    float inv = 1.0f / (li + __shfl_xor(li, 32));

    // O^T: lane holds q = q0+l31; rows hd = (reg&3)+8*(reg>>2)+4*half (+32 for o1)
    const int q = q0 + l31;
    size_t base = ((size_t)(b * SEQ + q)) * DIM + h * HD;
    #pragma unroll
    for (int g = 0; g < 4; ++g) {
        int hd0 = 8 * g + 4 * half;
        uint2 u0, u1;
        u0.x = cvtpk((o0a[4*g+0] + o0b[4*g+0]) * inv, (o0a[4*g+1] + o0b[4*g+1]) * inv);
        u0.y = cvtpk((o0a[4*g+2] + o0b[4*g+2]) * inv, (o0a[4*g+3] + o0b[4*g+3]) * inv);
        u1.x = cvtpk((o1a[4*g+0] + o1b[4*g+0]) * inv, (o1a[4*g+1] + o1b[4*g+1]) * inv);
        u1.y = cvtpk((o1a[4*g+2] + o1b[4*g+2]) * inv, (o1a[4*g+3] + o1b[4*g+3]) * inv);
        *reinterpret_cast<uint2*>(&ctx[base + hd0])      = u0;
        *reinterpret_cast<uint2*>(&ctx[base + 32 + hd0]) = u1;
    }
}

extern "C" void kernel_launch(void* const* d_in, const int* in_sizes, int n_in,
                              void* d_out, int out_size, void* d_ws, size_t ws_size,
                              hipStream_t stream) {
    const float* x  = (const float*)d_in[0];
    const float* qw = (const float*)d_in[1]; const float* qb = (const float*)d_in[2];
    const float* kw = (const float*)d_in[3]; const float* kb = (const float*)d_in[4];
    const float* vw = (const float*)d_in[5]; const float* vb = (const float*)d_in[6];
    const float* ow = (const float*)d_in[7]; const float* ob = (const float*)d_in[8];
    float* out = (float*)d_out;

    char* ws = (char*)d_ws;
    size_t off = 0;
    auto alloc = [&](size_t bytes) -> unsigned short* {
        unsigned short* p = (unsigned short*)(ws + off);
        off += (bytes + 255) & ~(size_t)255;
        return p;
    };
    const size_t XB = (size_t)MM * DIM * 2;
    const size_t WB = (size_t)DIM * DIM * 2;
    const size_t QB = (size_t)NB * NH * SEQ * HD * 2;

    unsigned short* xb  = alloc(XB);
    unsigned short* wqb = alloc(WB);
    unsigned short* wkb = alloc(WB);
    unsigned short* wvb = alloc(WB);
    unsigned short* wob = alloc(WB);
    unsigned short* Qb  = alloc(QB);
    unsigned short* Kfb = alloc(QB);   // fragment-native K
    unsigned short* Vfb = alloc(QB);   // fragment-native V
    unsigned short* ctx = alloc(XB);

    const int n4x = MM * DIM / 4;
    const int n4w = DIM * DIM / 4;
    cast_f32_bf16<<<(n4x + 255) / 256, 256, 0, stream>>>(x, xb, n4x);
    cast4_f32_bf16<<<dim3((n4w + 255) / 256, 4), 256, 0, stream>>>(
        qw, kw, vw, ow, wqb, wkb, wvb, wob, n4w);

    gemm_qkv<<<dim3(MM / 128, NH), 256, 0, stream>>>(
        xb, wqb, wkb, wvb, qb, kb, vb, Qb, Kfb, Vfb);

    attn<<<dim3(SEQ / 128, NB * NH), 256, 0, stream>>>(Qb, Kfb, Vfb, ctx);

    gemm_o<<<dim3(MM / 128, DIM / 64), 256, 0, stream>>>(ctx, wob, ob, out);
}